// Round 7
// baseline (7450.076 us; speedup 1.0000x reference)
//
#include <hip/hip_runtime.h>
#include <hip/hip_bf16.h>

// ---------------------------------------------------------------------------
// LocalizedPromptedAttentionLayer on MI355X (gfx950) — round 7
// B=32, N=576 patches, W=16 kv-window, d=768, P=4 prompts, H=12 heads, Dh=64
//
//   xb   = bf16(x)                                [18432, 1536]  (aliased in ob)
//   q_x  = xb @ (Wq@Wx)^T + (bq + Wq@bx)          [18432, 768] bf16   (128² GEMM)
//   qprm = prompt @ Wq^T + bq                     [4, 768] bf16
//   kv   = y_f32 @ [Wk@Wy ; Wv@Wy]^T + bias       [294912, 1536] bf16 (256² 8-phase,
//                                                  f32 A reg-staged + cvt fused)
//   o    = softmax(q k^T / 8) v                   [92160, 768] bf16
//   out  = o @ out_w^T + out_b                    [92160, 768] f32    (256² 8-phase)
//
// Round-7 fix vs round 6: A-f32 staging now has a FULL K-tile of lead.
// Iter u: P3 issues A(u+2) (after B(u+1) in vmcnt order), P4 cvt+ds_writes
// A(u+1) loaded one iteration earlier (reg-dep wait is a no-op by then).
// End-of-iter counted wait vmcnt(8) retires B(u+1), keeps A(u+2) in flight.
// Phase structure restored to the proven round-5 4-phase interleave.
// ---------------------------------------------------------------------------

typedef __attribute__((ext_vector_type(8))) short bf16x8;   // MFMA A/B frag
typedef __attribute__((ext_vector_type(4))) float f32x4;    // MFMA C/D frag
typedef __attribute__((ext_vector_type(8))) unsigned short u16x8;

__device__ __forceinline__ float bf2f(unsigned short u) {
  union { unsigned int i; float f; } x; x.i = ((unsigned int)u) << 16; return x.f;
}
__device__ __forceinline__ unsigned short f2b(float f) {
  union { float f; unsigned int i; } x; x.f = f;
  unsigned int u = x.i;
  return (unsigned short)((u + 0x7fffu + ((u >> 16) & 1u)) >> 16);  // RNE
}
__device__ __forceinline__ unsigned int cvtpk(float lo, float hi) {
  unsigned int r;
  asm("v_cvt_pk_bf16_f32 %0, %1, %2" : "=v"(r) : "v"(lo), "v"(hi));  // RNE pack
  return r;
}

#define GLDS(gaddr, laddr) \
  __builtin_amdgcn_global_load_lds( \
      (const __attribute__((address_space(1))) unsigned int*)(gaddr), \
      (__attribute__((address_space(3))) unsigned int*)(laddr), 16, 0, 0)

// ---------------- f32 -> bf16 bulk convert (8 elems/thread-iter) ----------------
__global__ void k_cvt(const float* __restrict__ src, unsigned short* __restrict__ dst, long n8) {
  long stride = (long)gridDim.x * blockDim.x;
  for (long i = (long)blockIdx.x * blockDim.x + threadIdx.x; i < n8; i += stride) {
    float4 a = ((const float4*)src)[2 * i];
    float4 b = ((const float4*)src)[2 * i + 1];
    u16x8 t = { f2b(a.x), f2b(a.y), f2b(a.z), f2b(a.w),
                f2b(b.x), f2b(b.y), f2b(b.z), f2b(b.w) };
    ((u16x8*)dst)[i] = t;
  }
}

// ---------------- weight fusion: C[j,i] = sum_k A[j,k] * B[k,i] (bf16 out) ----------------
__global__ __launch_bounds__(256) void k_wfuse(const float* __restrict__ A,
                                               const float* __restrict__ Bm,
                                               unsigned short* __restrict__ C,
                                               int K, int lda, int ncols) {
  int i  = blockIdx.x * 256 + threadIdx.x;
  int j0 = blockIdx.y * 8;
  float acc[8] = {0.f,0.f,0.f,0.f,0.f,0.f,0.f,0.f};
  for (int k = 0; k < K; ++k) {
    float wb = Bm[(long)k * ncols + i];
#pragma unroll
    for (int r = 0; r < 8; ++r) acc[r] += A[(long)(j0 + r) * lda + k] * wb;
  }
#pragma unroll
  for (int r = 0; r < 8; ++r) C[(long)(j0 + r) * ncols + i] = f2b(acc[r]);
}

// ---------------- fused biases ----------------
__global__ void k_bfuse(const float* __restrict__ ipw, const float* __restrict__ ipb,
                        const float* __restrict__ bx, const float* __restrict__ by,
                        float* __restrict__ bqx, float* __restrict__ bkv) {
  int o    = blockIdx.x * 4 + (threadIdx.x >> 6);   // 0..2303 (grid 576)
  int lane = threadIdx.x & 63;
  int sec  = o / 768, jj = o - sec * 768;
  const float* Arow = ipw + (long)o * 768;
  const float* vb   = (sec == 0) ? bx : by;
  float s = 0.f;
  for (int k = lane; k < 768; k += 64) s += Arow[k] * vb[k];
#pragma unroll
  for (int d = 32; d > 0; d >>= 1) s += __shfl_down(s, d);
  if (lane == 0) {
    s += ipb[o];
    if (sec == 0) bqx[jj] = s;
    else if (sec == 1) bkv[jj] = s;
    else bkv[768 + jj] = s;
  }
}

// ---------------- prompt queries ----------------
__global__ void k_qprompt(const float* __restrict__ ipw, const float* __restrict__ ipb,
                          const float* __restrict__ prompt, unsigned short* __restrict__ qpf) {
  int o    = blockIdx.x * 4 + (threadIdx.x >> 6);   // 0..3071 (grid 768)
  int lane = threadIdx.x & 63;
  int p = o / 768, j = o - p * 768;
  const float* Wqr = ipw + (long)j * 768;
  const float* pr  = prompt + (long)p * 768;
  float s = 0.f;
  for (int k = lane; k < 768; k += 64) s += Wqr[k] * pr[k];
#pragma unroll
  for (int d = 32; d > 0; d >>= 1) s += __shfl_down(s, d);
  if (lane == 0) qpf[o] = f2b(s + ipb[j]);
}

// ---------------- 128² GEMM (proven m97 structure) — used for q_x ----------------
template <typename OutT>
__global__ __launch_bounds__(256) void k_gemm(const unsigned short* __restrict__ A,
                                              const unsigned short* __restrict__ Bw,
                                              const float* __restrict__ bias,
                                              OutT* __restrict__ C,
                                              int M, int Nn, int K, int nbx) {
  const int tid  = threadIdx.x;
  const int lane = tid & 63, wid = tid >> 6;
  const int wm = wid >> 1, wn = wid & 1;
  const int lr = lane & 15, lk = lane >> 4;

  const int nwg = gridDim.x, orig = blockIdx.x;
  const int q8 = nwg >> 3, r8 = nwg & 7, xc = orig & 7;
  const int wg = (xc < r8 ? xc * (q8 + 1) : r8 * (q8 + 1) + (xc - r8) * q8) + (orig >> 3);
  const int bn = wg % nbx, bm = wg / nbx;
  const int m0 = bm * 128, n0 = bn * 128;

  __shared__ __attribute__((aligned(16))) unsigned short As[2][128 * 32];
  __shared__ __attribute__((aligned(16))) unsigned short Bs[2][128 * 32];

  f32x4 acc[4][4];
#pragma unroll
  for (int nt = 0; nt < 4; ++nt) {
    float bv = bias[n0 + wn * 64 + nt * 16 + lr];
    f32x4 bvv = {bv, bv, bv, bv};
#pragma unroll
    for (int mt = 0; mt < 4; ++mt) acc[mt][nt] = bvv;
  }

  const int NS = K >> 5;
  const int crow = lane >> 2, ck8 = (lane & 3) * 8;

  auto stage = [&](int buf, int ks) {
#pragma unroll
    for (int i = 0; i < 2; ++i) {
      int c = wid * 2 + i;
      int row = c * 16 + crow;
      GLDS(&A[(long)(m0 + row) * K + ks * 32 + ck8], &As[buf][c * 512]);
      GLDS(&Bw[(long)(n0 + row) * K + ks * 32 + ck8], &Bs[buf][c * 512]);
    }
  };

  stage(0, 0);
  __syncthreads();

  for (int t = 0; t < NS; ++t) {
    const int cur = t & 1, nb = cur ^ 1;
    if (t + 1 < NS) stage(nb, t + 1);
    bf16x8 af[4], bfr[4];
#pragma unroll
    for (int mt = 0; mt < 4; ++mt)
      af[mt] = *(const bf16x8*)&As[cur][(wm * 64 + mt * 16 + lr) * 32 + lk * 8];
#pragma unroll
    for (int nt = 0; nt < 4; ++nt)
      bfr[nt] = *(const bf16x8*)&Bs[cur][(wn * 64 + nt * 16 + lr) * 32 + lk * 8];
#pragma unroll
    for (int mt = 0; mt < 4; ++mt)
#pragma unroll
      for (int nt = 0; nt < 4; ++nt)
        acc[mt][nt] = __builtin_amdgcn_mfma_f32_16x16x32_bf16(af[mt], bfr[nt], acc[mt][nt], 0, 0, 0);
    __syncthreads();
  }

#pragma unroll
  for (int mt = 0; mt < 4; ++mt)
#pragma unroll
    for (int nt = 0; nt < 4; ++nt) {
      int col = n0 + wn * 64 + nt * 16 + lr;
#pragma unroll
      for (int r = 0; r < 4; ++r) {
        int row = m0 + wm * 64 + mt * 16 + lk * 4 + r;
        float v = acc[mt][nt][r];
        if constexpr (sizeof(OutT) == 4) C[(long)row * Nn + col] = v;
        else                             C[(long)row * Nn + col] = f2b(v);
      }
    }
}

// ---------------- 256² 8-phase GEMM (T2+T3+T4+T5) ----------------
// 512 thr = 8 waves (2M x 4N), BM=BN=256, BK=64, per-wave C = 128x64.
// LDS 128 KiB, st_16x32 XOR swizzle. Counted vmcnt; all cross-wave publishes
// drained (vmcnt/lgkmcnt) BEFORE the closing barrier (round-5 rule).
// AF32=true: A f32 reg-staged with FULL-TILE lead: iter u P3 issues A(u+2)
// (after B(u+1)), P4 cvt+ds_writes A(u+1). End-of-iter vmcnt(8) retires
// B(u+1), keeps A(u+2) in flight. AF32=false: round-5 schedule, unchanged.
template <bool AF32, typename OutT>
__global__ __launch_bounds__(512, 2) void k_gemm8(const void* __restrict__ Ap,
                                                  const unsigned short* __restrict__ Bw,
                                                  const float* __restrict__ bias,
                                                  OutT* __restrict__ C,
                                                  int M, int Nn, int K, int nbx) {
  const int tid  = threadIdx.x;
  const int lane = tid & 63, wid = tid >> 6;
  const int wm = wid >> 2, wn = wid & 3;          // 2 x 4 waves
  const int lr = lane & 15, lk = lane >> 4;

  const int nwg = gridDim.x, orig = blockIdx.x;
  const int q8 = nwg >> 3, r8 = nwg & 7, xc = orig & 7;
  const int wg = (xc < r8 ? xc * (q8 + 1) : r8 * (q8 + 1) + (xc - r8) * q8) + (orig >> 3);
  const int bn = wg % nbx, bm = wg / nbx;
  const long m0 = (long)bm * 256, n0 = (long)bn * 256;

  const float*          Af = (const float*)Ap;
  const unsigned short* Ab = (const unsigned short*)Ap;

  __shared__ __attribute__((aligned(16))) unsigned short As[2][2][8192];  // [buf][half][128*64]
  __shared__ __attribute__((aligned(16))) unsigned short Bs[2][2][8192];

  f32x4 acc[8][4];
#pragma unroll
  for (int nt = 0; nt < 4; ++nt) {
    float bv = bias[n0 + wn * 64 + nt * 16 + lr];
    f32x4 bvv = {bv, bv, bv, bv};
#pragma unroll
    for (int mt = 0; mt < 8; ++mt) acc[mt][nt] = bvv;
  }

  const int NT = K >> 6;            // K-tiles of 64

  // stage one half-tile via global_load_lds (dest linear, source pre-swizzled)
  auto stage = [&](int buf, int kt, int isB, int h) {
#pragma unroll
    for (int j = 0; j < 2; ++j) {
      int c   = j * 8 + wid;                         // 1KB chunk 0..15 (wave-uniform)
      int row = c * 8 + (lane >> 3);                 // 0..127
      int col = ((lane & 7) * 8) ^ ((row & 7) << 3); // elems, inverse-swizzled
      const unsigned short* g = isB
          ? &Bw[(n0 + h * 128 + row) * (long)K + kt * 64 + col]
          : &Ab[(m0 + h * 128 + row) * (long)K + kt * 64 + col];
      unsigned short* l = isB ? &Bs[buf][h][c * 512] : &As[buf][h][c * 512];
      GLDS(g, l);
    }
  };

  // ---- AF32 A-path: f32 reg-stage (two named buffers) + cvt + swizzled ds_write ----
  const int ar = tid >> 2, aq = tid & 3;  // row 0..127, col-quarter (16 f32)
  float4 raA[8], raB[8];                  // [h*4 + i] ; rule #20: no runtime idx
  auto issueA = [&](int kt, float4 (&dst)[8]) {
#pragma unroll
    for (int h = 0; h < 2; ++h)
#pragma unroll
      for (int i = 0; i < 4; ++i)
        dst[h * 4 + i] = *(const float4*)&Af[(m0 + h * 128 + ar) * (long)K + kt * 64 + aq * 16 + i * 4];
  };
  auto writeA = [&](int buf, float4 (&src)[8]) {
#pragma unroll
    for (int h = 0; h < 2; ++h) {
#pragma unroll
      for (int s = 0; s < 2; ++s) {
        unsigned int w0 = cvtpk(src[h * 4 + 2 * s].x,     src[h * 4 + 2 * s].y);
        unsigned int w1 = cvtpk(src[h * 4 + 2 * s].z,     src[h * 4 + 2 * s].w);
        unsigned int w2 = cvtpk(src[h * 4 + 2 * s + 1].x, src[h * 4 + 2 * s + 1].y);
        unsigned int w3 = cvtpk(src[h * 4 + 2 * s + 1].z, src[h * 4 + 2 * s + 1].w);
        int col = (aq * 16 + s * 8) ^ ((ar & 7) << 3);   // swizzled elem col
        uint4 pk = {w0, w1, w2, w3};
        *(uint4*)&As[buf][h][ar * 64 + col] = pk;        // ds_write_b128
      }
    }
  };

  // swizzled ds_read of one 16x32 MFMA A/B fragment
  auto ldsA = [&](int buf, int mt, int kk) -> bf16x8 {
    int r = mt * 16 + lr;
    int off = r * 128 + ((kk * 64 + lk * 16) ^ ((lr & 7) << 4));   // bytes
    return *(const bf16x8*)((const char*)&As[buf][wm][0] + off);
  };
  auto ldsB = [&](int buf, int nt, int kk) -> bf16x8 {
    int r = (wn & 1) * 64 + nt * 16 + lr;
    int off = r * 128 + ((kk * 64 + lk * 16) ^ ((lr & 7) << 4));
    return *(const bf16x8*)((const char*)&Bs[buf][wn >> 1][0] + off);
  };

  // ---- prologue ----
  if constexpr (AF32) {
    issueA(0, raB);                         // A(0): iter0's "cur" slot is raB
    stage(0, 0, 1, 0); stage(0, 0, 1, 1);   // B(0)
    writeA(0, raB);                         // compiler reg-dep waits A(0)
    if (NT > 1) issueA(1, raB);             // A(1) -> raB (iter0 cur), after B(0)
    asm volatile("s_waitcnt vmcnt(8) lgkmcnt(0)" ::: "memory");  // B(0) landed; A(1) in flight
  } else {
    stage(0, 0, 0, 0); stage(0, 0, 0, 1); stage(0, 0, 1, 0); stage(0, 0, 1, 1);
    if (NT > 1) {
      stage(1, 1, 0, 0);
      asm volatile("s_waitcnt vmcnt(2)" ::: "memory");
    } else {
      asm volatile("s_waitcnt vmcnt(0)" ::: "memory");
    }
  }
  __builtin_amdgcn_s_barrier();

  for (int u = 0; u < NT; ++u) {
    const int cb = u & 1;
    const bool nx = (u + 1 < NT);
    bf16x8 a[4][2], b0[2][2], b1[2][2];

    if constexpr (AF32) {
      // ---- P1: ds_read A(0-3)+B(0-1); stage B h0 (u+1); MFMA (0-3)x(0-1) ----
#pragma unroll
      for (int mt = 0; mt < 4; ++mt) { a[mt][0] = ldsA(cb, mt, 0); a[mt][1] = ldsA(cb, mt, 1); }
#pragma unroll
      for (int nt = 0; nt < 2; ++nt) { b0[nt][0] = ldsB(cb, nt, 0); b0[nt][1] = ldsB(cb, nt, 1); }
      if (nx) stage(cb ^ 1, u + 1, 1, 0);
      __builtin_amdgcn_s_barrier();
      asm volatile("s_waitcnt lgkmcnt(0)" ::: "memory");
      __builtin_amdgcn_s_setprio(1);
#pragma unroll
      for (int mt = 0; mt < 4; ++mt)
#pragma unroll
        for (int nt = 0; nt < 2; ++nt)
#pragma unroll
          for (int kk = 0; kk < 2; ++kk)
            acc[mt][nt] = __builtin_amdgcn_mfma_f32_16x16x32_bf16(a[mt][kk], b0[nt][kk], acc[mt][nt], 0, 0, 0);
      __builtin_amdgcn_s_setprio(0);
      __builtin_amdgcn_s_barrier();

      // ---- P2: ds_read B(2-3); stage B h1 (u+1); MFMA (0-3)x(2-3) ----
#pragma unroll
      for (int nt = 0; nt < 2; ++nt) { b1[nt][0] = ldsB(cb, 2 + nt, 0); b1[nt][1] = ldsB(cb, 2 + nt, 1); }
      if (nx) stage(cb ^ 1, u + 1, 1, 1);
      __builtin_amdgcn_s_barrier();
      asm volatile("s_waitcnt lgkmcnt(0)" ::: "memory");
      __builtin_amdgcn_s_setprio(1);
#pragma unroll
      for (int mt = 0; mt < 4; ++mt)
#pragma unroll
        for (int nt = 0; nt < 2; ++nt)
#pragma unroll
          for (int kk = 0; kk < 2; ++kk)
            acc[mt][2 + nt] = __builtin_amdgcn_mfma_f32_16x16x32_bf16(a[mt][kk], b1[nt][kk], acc[mt][2 + nt], 0, 0, 0);
      __builtin_amdgcn_s_setprio(0);
      __builtin_amdgcn_s_barrier();

      // ---- P3: ds_read A(4-7); issue A-f32(u+2) into "next" buf; MFMA (4-7)x(2-3) ----
#pragma unroll
      for (int mt = 0; mt < 4; ++mt) { a[mt][0] = ldsA(cb, 4 + mt, 0); a[mt][1] = ldsA(cb, 4 + mt, 1); }
      if (u + 2 < NT) {
        if (u & 1) issueA(u + 2, raB);      // iter odd: next = raB
        else       issueA(u + 2, raA);      // iter even: next = raA
      }
      __builtin_amdgcn_s_barrier();
      asm volatile("s_waitcnt lgkmcnt(0)" ::: "memory");
      __builtin_amdgcn_s_setprio(1);
#pragma unroll
      for (int mt = 0; mt < 4; ++mt)
#pragma unroll
        for (int nt = 0; nt < 2; ++nt)
#pragma unroll
          for (int kk = 0; kk < 2; ++kk)
            acc[4 + mt][2 + nt] = __builtin_amdgcn_mfma_f32_16x16x32_bf16(a[mt][kk], b1[nt][kk], acc[4 + mt][2 + nt], 0, 0, 0);
      __builtin_amdgcn_s_setprio(0);
      __builtin_amdgcn_s_barrier();

      // ---- P4: cvt+ds_write A(u+1) (loaded last iter; reg-dep wait ~free); MFMA (4-7)x(0-1) ----
      if (nx) {
        if (u & 1) writeA(cb ^ 1, raA);     // iter odd: cur = raA
        else       writeA(cb ^ 1, raB);     // iter even: cur = raB
      }
      __builtin_amdgcn_s_barrier();
      __builtin_amdgcn_s_setprio(1);
#pragma unroll
      for (int mt = 0; mt < 4; ++mt)
#pragma unroll
        for (int nt = 0; nt < 2; ++nt)
#pragma unroll
          for (int kk = 0; kk < 2; ++kk)
            acc[4 + mt][nt] = __builtin_amdgcn_mfma_f32_16x16x32_bf16(a[mt][kk], b0[nt][kk], acc[4 + mt][nt], 0, 0, 0);
      __builtin_amdgcn_s_setprio(0);
      // publish BEFORE closing barrier: retire B(u+1) glds + this wave's
      // ds_writes; keep A(u+2) f32 loads (8 newest) in flight.
      if (u + 2 < NT)       asm volatile("s_waitcnt vmcnt(8) lgkmcnt(0)" ::: "memory");
      else if (nx)          asm volatile("s_waitcnt vmcnt(0) lgkmcnt(0)" ::: "memory");
      __builtin_amdgcn_s_barrier();
    } else {
      // ================= round-5 schedule (A bf16 via glds) =================
      // ---- P1 ----
#pragma unroll
      for (int mt = 0; mt < 4; ++mt) { a[mt][0] = ldsA(cb, mt, 0); a[mt][1] = ldsA(cb, mt, 1); }
#pragma unroll
      for (int nt = 0; nt < 2; ++nt) { b0[nt][0] = ldsB(cb, nt, 0); b0[nt][1] = ldsB(cb, nt, 1); }
      if (nx) stage(cb ^ 1, u + 1, 0, 1);
      __builtin_amdgcn_s_barrier();
      asm volatile("s_waitcnt lgkmcnt(0)" ::: "memory");
      __builtin_amdgcn_s_setprio(1);
#pragma unroll
      for (int mt = 0; mt < 4; ++mt)
#pragma unroll
        for (int nt = 0; nt < 2; ++nt)
#pragma unroll
          for (int kk = 0; kk < 2; ++kk)
            acc[mt][nt] = __builtin_amdgcn_mfma_f32_16x16x32_bf16(a[mt][kk], b0[nt][kk], acc[mt][nt], 0, 0, 0);
      __builtin_amdgcn_s_setprio(0);
      __builtin_amdgcn_s_barrier();

      // ---- P2 ----
#pragma unroll
      for (int nt = 0; nt < 2; ++nt) { b1[nt][0] = ldsB(cb, 2 + nt, 0); b1[nt][1] = ldsB(cb, 2 + nt, 1); }
      if (nx) stage(cb ^ 1, u + 1, 1, 0);
      __builtin_amdgcn_s_barrier();
      asm volatile("s_waitcnt lgkmcnt(0)" ::: "memory");
      __builtin_amdgcn_s_setprio(1);
#pragma unroll
      for (int mt = 0; mt < 4; ++mt)
#pragma unroll
        for (int nt = 0; nt < 2; ++nt)
#pragma unroll
          for (int kk = 0; kk < 2; ++kk)
            acc[mt][2 + nt] = __builtin_amdgcn_mfma_f32_16x16x32_bf16(a[mt][kk], b1[nt][kk], acc[mt][2 + nt], 0, 0, 0);
      __builtin_amdgcn_s_setprio(0);
      __builtin_amdgcn_s_barrier();

      // ---- P3 ----
#pragma unroll
      for (int mt = 0; mt < 4; ++mt) { a[mt][0] = ldsA(cb, 4 + mt, 0); a[mt][1] = ldsA(cb, 4 + mt, 1); }
      if (nx) stage(cb ^ 1, u + 1, 1, 1);
      __builtin_amdgcn_s_barrier();
      asm volatile("s_waitcnt lgkmcnt(0)" ::: "memory");
      __builtin_amdgcn_s_setprio(1);
#pragma unroll
      for (int mt = 0; mt < 4; ++mt)
#pragma unroll
        for (int nt = 0; nt < 2; ++nt)
#pragma unroll
          for (int kk = 0; kk < 2; ++kk)
            acc[4 + mt][2 + nt] = __builtin_amdgcn_mfma_f32_16x16x32_bf16(a[mt][kk], b1[nt][kk], acc[4 + mt][2 + nt], 0, 0, 0);
      __builtin_amdgcn_s_setprio(0);
      __builtin_amdgcn_s_barrier();

      // ---- P4 ----
      if (u + 2 < NT) stage(cb, u + 2, 0, 0);
      __builtin_amdgcn_s_barrier();
      __builtin_amdgcn_s_setprio(1);
#pragma unroll
      for (int mt = 0; mt < 4; ++mt)
#pragma unroll
        for (int nt = 0; nt < 2; ++nt)
#pragma unroll
          for (int kk = 0; kk < 2; ++kk)
            acc[4 + mt][nt] = __builtin_amdgcn_mfma_f32_16x16x32_bf16(a[mt][kk], b0[nt][kk], acc[4 + mt][nt], 0, 0, 0);
      __builtin_amdgcn_s_setprio(0);
      if (u + 2 < NT)       asm volatile("s_waitcnt vmcnt(2)" ::: "memory");
      else if (u + 1 < NT)  asm volatile("s_waitcnt vmcnt(0)" ::: "memory");
      __builtin_amdgcn_s_barrier();
    }
  }

  // ---- epilogue ----
#pragma unroll
  for (int mt = 0; mt < 8; ++mt)
#pragma unroll
    for (int nt = 0; nt < 4; ++nt) {
      long col = n0 + wn * 64 + nt * 16 + lr;
#pragma unroll
      for (int r = 0; r < 4; ++r) {
        long row = m0 + wm * 128 + mt * 16 + lk * 4 + r;
        float v = acc[mt][nt][r];
        if constexpr (sizeof(OutT) == 4) C[row * Nn + col] = v;
        else                             C[row * Nn + col] = f2b(v);
      }
    }
}

// ---------------- attention, coalesced ----------------
__global__ __launch_bounds__(512) void k_attn(const unsigned short* __restrict__ kv,
                                              const unsigned short* __restrict__ qx,
                                              const unsigned short* __restrict__ qp,
                                              unsigned short* __restrict__ o) {
  __shared__ unsigned short Ks[32 * 772];
  __shared__ unsigned short Qs[6 * 768];
  __shared__ float Ss[120 * 16];
  const int tid = threadIdx.x;
  const long p0 = (long)blockIdx.x * 2;

  for (int i = tid; i < 32 * 96; i += 512) {
    int r = i / 96, c8 = i - (i / 96) * 96;
    u16x8 vv = *(const u16x8*)&kv[((p0 + (r >> 4)) * 16 + (r & 15)) * 1536 + c8 * 8];
    *(u16x8*)&Ks[r * 772 + c8 * 8] = vv;
  }
  for (int i = tid; i < 6 * 96; i += 512) {
    int r = i / 96, c8 = i - (i / 96) * 96;
    const unsigned short* src = (r < 2) ? &qx[(p0 + r) * 768 + c8 * 8]
                                        : &qp[(long)(r - 2) * 768 + c8 * 8];
    *(u16x8*)&Qs[r * 768 + c8 * 8] = *(const u16x8*)src;
  }
  __syncthreads();

  for (int idx = tid; idx < 1920; idx += 512) {
    int w = idx & 15, rest = idx >> 4;
    int h = rest % 12, pq = rest / 12;
    int q5 = pq % 5, p = pq / 5;
    const unsigned short* krow = &Ks[(p * 16 + w) * 772 + h * 64];
    const unsigned short* qrow = &Qs[((q5 == 0) ? p : 1 + q5) * 768 + h * 64];
    float s = 0.f;
#pragma unroll
    for (int j = 0; j < 8; ++j) {
      u16x8 kk = *(const u16x8*)&krow[j * 8];
      u16x8 qq = *(const u16x8*)&qrow[j * 8];
#pragma unroll
      for (int e = 0; e < 8; ++e) s += bf2f(qq[e]) * bf2f(kk[e]);
    }
    s *= 0.125f;
    float m = s;
#pragma unroll
    for (int d = 1; d < 16; d <<= 1) m = fmaxf(m, __shfl_xor(m, d));
    float e = __expf(s - m);
    float sum = e;
#pragma unroll
    for (int d = 1; d < 16; d <<= 1) sum += __shfl_xor(sum, d);
    Ss[rest * 16 + w] = e / sum;
  }
  __syncthreads();

  for (int idx = tid; idx < 960; idx += 512) {
    int d8 = idx % 96, pq = idx / 96;
    int q5 = pq % 5, p = pq / 5, h = d8 >> 3;
    const float* arow = &Ss[(pq * 12 + h) * 16];
    const unsigned short* vbase = &kv[(p0 + p) * 16 * 1536 + 768 + d8 * 8];
    float acc[8] = {0.f,0.f,0.f,0.f,0.f,0.f,0.f,0.f};
#pragma unroll
    for (int w = 0; w < 16; ++w) {
      u16x8 vv = *(const u16x8*)&vbase[(long)w * 1536];
      float aw = arow[w];
#pragma unroll
      for (int e = 0; e < 8; ++e) acc[e] += aw * bf2f(vv[e]);
    }
    u16x8 ov;
#pragma unroll
    for (int e = 0; e < 8; ++e) ov[e] = f2b(acc[e]);
    *(u16x8*)&o[((p0 + p) * 5 + q5) * 768 + d8 * 8] = ov;
  }
}

// ---------------------------------------------------------------------------
extern "C" void kernel_launch(void* const* d_in, const int* in_sizes, int n_in,
                              void* d_out, int out_size, void* d_ws, size_t ws_size,
                              hipStream_t stream) {
  const float* x      = (const float*)d_in[0];   // [32,576,1536]
  const float* y      = (const float*)d_in[1];   // [32,9216,1024]
  const float* Wx     = (const float*)d_in[2];   // [768,1536]
  const float* bx     = (const float*)d_in[3];   // [768]
  const float* Wy     = (const float*)d_in[4];   // [768,1024]
  const float* by     = (const float*)d_in[5];   // [768]
  const float* prompt = (const float*)d_in[6];   // [1,4,768]
  const float* ipw    = (const float*)d_in[7];   // [2304,768]
  const float* ipb    = (const float*)d_in[8];   // [2304]
  const float* outw   = (const float*)d_in[9];   // [768,768]
  const float* outb   = (const float*)d_in[10];  // [768]
  float* out = (float*)d_out;

  char* ws = (char*)d_ws;
  size_t off = 0;
  auto alloc = [&](size_t bytes) -> void* {
    void* p = ws + off; off += (bytes + 255) & ~(size_t)255; return p;
  };
  unsigned short* kvb  = (unsigned short*)alloc(294912UL * 1536 * 2);  // 906 MB
  unsigned short* qxb  = (unsigned short*)alloc(18432UL * 768 * 2);    // 28 MB
  unsigned short* ob   = (unsigned short*)alloc(92160UL * 768 * 2);    // 142 MB
  unsigned short* Wqx  = (unsigned short*)alloc(768UL * 1536 * 2);
  unsigned short* Wkv  = (unsigned short*)alloc(1536UL * 1024 * 2);
  unsigned short* oww  = (unsigned short*)alloc(768UL * 768 * 2);
  unsigned short* qpf  = (unsigned short*)alloc(4UL * 768 * 2);
  float*          bqx  = (float*)alloc(768 * 4);
  float*          bkv  = (float*)alloc(1536 * 4);
  unsigned short* xb   = ob;  // alias (dead before k_attn writes ob)

  // ---- weight prep ----
  k_cvt<<<dim3(288), dim3(256), 0, stream>>>(outw, oww, 768L * 768 / 8);
  k_wfuse<<<dim3(6, 96), dim3(256), 0, stream>>>(ipw,              Wx, Wqx,              768, 768, 1536);
  k_wfuse<<<dim3(4, 96), dim3(256), 0, stream>>>(ipw + 768 * 768,  Wy, Wkv,              768, 768, 1024);
  k_wfuse<<<dim3(4, 96), dim3(256), 0, stream>>>(ipw + 1536 * 768, Wy, Wkv + 768 * 1024, 768, 768, 1024);
  k_bfuse<<<dim3(576), dim3(256), 0, stream>>>(ipw, ipb, bx, by, bqx, bkv);
  k_qprompt<<<dim3(768), dim3(256), 0, stream>>>(ipw, ipb, prompt, qpf);

  // ---- x -> bf16; q_x = xb @ Wqx^T + bqx  (M=18432, N=768, K=1536) ----
  k_cvt<<<dim3(2048), dim3(256), 0, stream>>>(x, xb, 18432L * 1536 / 8);
  k_gemm<unsigned short><<<dim3(144 * 6), dim3(256), 0, stream>>>(
      xb, Wqx, bqx, qxb, 18432, 768, 1536, 6);

  // ---- kv = y_f32 @ Wkv^T + bkv  (M=294912, N=1536, K=1024), cvt fused ----
  k_gemm8<true, unsigned short><<<dim3(1152 * 6), dim3(512), 0, stream>>>(
      (const void*)y, Wkv, bkv, kvb, 294912, 1536, 1024, 6);

  // ---- attention -> o bf16 ----
  k_attn<<<dim3(9216), dim3(512), 0, stream>>>(kvb, qxb, qpf, ob);

  // ---- out = o @ oww^T + outb  (M=92160, N=768, K=768) -> f32, 8-phase ----
  k_gemm8<false, float><<<dim3(360 * 3), dim3(512), 0, stream>>>(
      (const void*)ob, oww, outb, out, 92160, 768, 768, 3);
}

// Round 8
// 7448.038 us; speedup vs baseline: 1.0003x; 1.0003x over previous
//
#include <hip/hip_runtime.h>
#include <hip/hip_bf16.h>

// ---------------------------------------------------------------------------
// LocalizedPromptedAttentionLayer on MI355X (gfx950) — round 7
// B=32, N=576 patches, W=16 kv-window, d=768, P=4 prompts, H=12 heads, Dh=64
//
//   xb   = bf16(x)                                [18432, 1536]  (aliased in ob)
//   q_x  = xb @ (Wq@Wx)^T + (bq + Wq@bx)          [18432, 768] bf16   (128² GEMM)
//   qprm = prompt @ Wq^T + bq                     [4, 768] bf16
//   kv   = y_f32 @ [Wk@Wy ; Wv@Wy]^T + bias       [294912, 1536] bf16 (256² 8-phase,
//                                                  f32 A reg-staged + cvt fused)
//   o    = softmax(q k^T / 8) v                   [92160, 768] bf16
//   out  = o @ out_w^T + out_b                    [92160, 768] f32    (256² 8-phase)
//
// Round-7 fix vs round 6: A-f32 staging now has a FULL K-tile of lead.
// Iter u: P3 issues A(u+2) (after B(u+1) in vmcnt order), P4 cvt+ds_writes
// A(u+1) loaded one iteration earlier (reg-dep wait is a no-op by then).
// End-of-iter counted wait vmcnt(8) retires B(u+1), keeps A(u+2) in flight.
// Phase structure restored to the proven round-5 4-phase interleave.
// ---------------------------------------------------------------------------

typedef __attribute__((ext_vector_type(8))) short bf16x8;   // MFMA A/B frag
typedef __attribute__((ext_vector_type(4))) float f32x4;    // MFMA C/D frag
typedef __attribute__((ext_vector_type(8))) unsigned short u16x8;

__device__ __forceinline__ float bf2f(unsigned short u) {
  union { unsigned int i; float f; } x; x.i = ((unsigned int)u) << 16; return x.f;
}
__device__ __forceinline__ unsigned short f2b(float f) {
  union { float f; unsigned int i; } x; x.f = f;
  unsigned int u = x.i;
  return (unsigned short)((u + 0x7fffu + ((u >> 16) & 1u)) >> 16);  // RNE
}
__device__ __forceinline__ unsigned int cvtpk(float lo, float hi) {
  unsigned int r;
  asm("v_cvt_pk_bf16_f32 %0, %1, %2" : "=v"(r) : "v"(lo), "v"(hi));  // RNE pack
  return r;
}

#define GLDS(gaddr, laddr) \
  __builtin_amdgcn_global_load_lds( \
      (const __attribute__((address_space(1))) unsigned int*)(gaddr), \
      (__attribute__((address_space(3))) unsigned int*)(laddr), 16, 0, 0)

// ---------------- f32 -> bf16 bulk convert (8 elems/thread-iter) ----------------
__global__ void k_cvt(const float* __restrict__ src, unsigned short* __restrict__ dst, long n8) {
  long stride = (long)gridDim.x * blockDim.x;
  for (long i = (long)blockIdx.x * blockDim.x + threadIdx.x; i < n8; i += stride) {
    float4 a = ((const float4*)src)[2 * i];
    float4 b = ((const float4*)src)[2 * i + 1];
    u16x8 t = { f2b(a.x), f2b(a.y), f2b(a.z), f2b(a.w),
                f2b(b.x), f2b(b.y), f2b(b.z), f2b(b.w) };
    ((u16x8*)dst)[i] = t;
  }
}

// ---------------- weight fusion: C[j,i] = sum_k A[j,k] * B[k,i] (bf16 out) ----------------
__global__ __launch_bounds__(256) void k_wfuse(const float* __restrict__ A,
                                               const float* __restrict__ Bm,
                                               unsigned short* __restrict__ C,
                                               int K, int lda, int ncols) {
  int i  = blockIdx.x * 256 + threadIdx.x;
  int j0 = blockIdx.y * 8;
  float acc[8] = {0.f,0.f,0.f,0.f,0.f,0.f,0.f,0.f};
  for (int k = 0; k < K; ++k) {
    float wb = Bm[(long)k * ncols + i];
#pragma unroll
    for (int r = 0; r < 8; ++r) acc[r] += A[(long)(j0 + r) * lda + k] * wb;
  }
#pragma unroll
  for (int r = 0; r < 8; ++r) C[(long)(j0 + r) * ncols + i] = f2b(acc[r]);
}

// ---------------- fused biases ----------------
__global__ void k_bfuse(const float* __restrict__ ipw, const float* __restrict__ ipb,
                        const float* __restrict__ bx, const float* __restrict__ by,
                        float* __restrict__ bqx, float* __restrict__ bkv) {
  int o    = blockIdx.x * 4 + (threadIdx.x >> 6);   // 0..2303 (grid 576)
  int lane = threadIdx.x & 63;
  int sec  = o / 768, jj = o - sec * 768;
  const float* Arow = ipw + (long)o * 768;
  const float* vb   = (sec == 0) ? bx : by;
  float s = 0.f;
  for (int k = lane; k < 768; k += 64) s += Arow[k] * vb[k];
#pragma unroll
  for (int d = 32; d > 0; d >>= 1) s += __shfl_down(s, d);
  if (lane == 0) {
    s += ipb[o];
    if (sec == 0) bqx[jj] = s;
    else if (sec == 1) bkv[jj] = s;
    else bkv[768 + jj] = s;
  }
}

// ---------------- prompt queries ----------------
__global__ void k_qprompt(const float* __restrict__ ipw, const float* __restrict__ ipb,
                          const float* __restrict__ prompt, unsigned short* __restrict__ qpf) {
  int o    = blockIdx.x * 4 + (threadIdx.x >> 6);   // 0..3071 (grid 768)
  int lane = threadIdx.x & 63;
  int p = o / 768, j = o - p * 768;
  const float* Wqr = ipw + (long)j * 768;
  const float* pr  = prompt + (long)p * 768;
  float s = 0.f;
  for (int k = lane; k < 768; k += 64) s += Wqr[k] * pr[k];
#pragma unroll
  for (int d = 32; d > 0; d >>= 1) s += __shfl_down(s, d);
  if (lane == 0) qpf[o] = f2b(s + ipb[j]);
}

// ---------------- 128² GEMM (proven m97 structure) — used for q_x ----------------
template <typename OutT>
__global__ __launch_bounds__(256) void k_gemm(const unsigned short* __restrict__ A,
                                              const unsigned short* __restrict__ Bw,
                                              const float* __restrict__ bias,
                                              OutT* __restrict__ C,
                                              int M, int Nn, int K, int nbx) {
  const int tid  = threadIdx.x;
  const int lane = tid & 63, wid = tid >> 6;
  const int wm = wid >> 1, wn = wid & 1;
  const int lr = lane & 15, lk = lane >> 4;

  const int nwg = gridDim.x, orig = blockIdx.x;
  const int q8 = nwg >> 3, r8 = nwg & 7, xc = orig & 7;
  const int wg = (xc < r8 ? xc * (q8 + 1) : r8 * (q8 + 1) + (xc - r8) * q8) + (orig >> 3);
  const int bn = wg % nbx, bm = wg / nbx;
  const int m0 = bm * 128, n0 = bn * 128;

  __shared__ __attribute__((aligned(16))) unsigned short As[2][128 * 32];
  __shared__ __attribute__((aligned(16))) unsigned short Bs[2][128 * 32];

  f32x4 acc[4][4];
#pragma unroll
  for (int nt = 0; nt < 4; ++nt) {
    float bv = bias[n0 + wn * 64 + nt * 16 + lr];
    f32x4 bvv = {bv, bv, bv, bv};
#pragma unroll
    for (int mt = 0; mt < 4; ++mt) acc[mt][nt] = bvv;
  }

  const int NS = K >> 5;
  const int crow = lane >> 2, ck8 = (lane & 3) * 8;

  auto stage = [&](int buf, int ks) {
#pragma unroll
    for (int i = 0; i < 2; ++i) {
      int c = wid * 2 + i;
      int row = c * 16 + crow;
      GLDS(&A[(long)(m0 + row) * K + ks * 32 + ck8], &As[buf][c * 512]);
      GLDS(&Bw[(long)(n0 + row) * K + ks * 32 + ck8], &Bs[buf][c * 512]);
    }
  };

  stage(0, 0);
  __syncthreads();

  for (int t = 0; t < NS; ++t) {
    const int cur = t & 1, nb = cur ^ 1;
    if (t + 1 < NS) stage(nb, t + 1);
    bf16x8 af[4], bfr[4];
#pragma unroll
    for (int mt = 0; mt < 4; ++mt)
      af[mt] = *(const bf16x8*)&As[cur][(wm * 64 + mt * 16 + lr) * 32 + lk * 8];
#pragma unroll
    for (int nt = 0; nt < 4; ++nt)
      bfr[nt] = *(const bf16x8*)&Bs[cur][(wn * 64 + nt * 16 + lr) * 32 + lk * 8];
#pragma unroll
    for (int mt = 0; mt < 4; ++mt)
#pragma unroll
      for (int nt = 0; nt < 4; ++nt)
        acc[mt][nt] = __builtin_amdgcn_mfma_f32_16x16x32_bf16(af[mt], bfr[nt], acc[mt][nt], 0, 0, 0);
    __syncthreads();
  }

#pragma unroll
  for (int mt = 0; mt < 4; ++mt)
#pragma unroll
    for (int nt = 0; nt < 4; ++nt) {
      int col = n0 + wn * 64 + nt * 16 + lr;
#pragma unroll
      for (int r = 0; r < 4; ++r) {
        int row = m0 + wm * 64 + mt * 16 + lk * 4 + r;
        float v = acc[mt][nt][r];
        if constexpr (sizeof(OutT) == 4) C[(long)row * Nn + col] = v;
        else                             C[(long)row * Nn + col] = f2b(v);
      }
    }
}

// ---------------- 256² 8-phase GEMM (T2+T3+T4+T5) ----------------
// 512 thr = 8 waves (2M x 4N), BM=BN=256, BK=64, per-wave C = 128x64.
// LDS 128 KiB, st_16x32 XOR swizzle. Counted vmcnt; all cross-wave publishes
// drained (vmcnt/lgkmcnt) BEFORE the closing barrier (round-5 rule).
// AF32=true: A f32 reg-staged with FULL-TILE lead: iter u P3 issues A(u+2)
// (after B(u+1)), P4 cvt+ds_writes A(u+1). End-of-iter vmcnt(8) retires
// B(u+1), keeps A(u+2) in flight. AF32=false: round-5 schedule, unchanged.
template <bool AF32, typename OutT>
__global__ __launch_bounds__(512, 2) void k_gemm8(const void* __restrict__ Ap,
                                                  const unsigned short* __restrict__ Bw,
                                                  const float* __restrict__ bias,
                                                  OutT* __restrict__ C,
                                                  int M, int Nn, int K, int nbx) {
  const int tid  = threadIdx.x;
  const int lane = tid & 63, wid = tid >> 6;
  const int wm = wid >> 2, wn = wid & 3;          // 2 x 4 waves
  const int lr = lane & 15, lk = lane >> 4;

  const int nwg = gridDim.x, orig = blockIdx.x;
  const int q8 = nwg >> 3, r8 = nwg & 7, xc = orig & 7;
  const int wg = (xc < r8 ? xc * (q8 + 1) : r8 * (q8 + 1) + (xc - r8) * q8) + (orig >> 3);
  const int bn = wg % nbx, bm = wg / nbx;
  const long m0 = (long)bm * 256, n0 = (long)bn * 256;

  const float*          Af = (const float*)Ap;
  const unsigned short* Ab = (const unsigned short*)Ap;

  __shared__ __attribute__((aligned(16))) unsigned short As[2][2][8192];  // [buf][half][128*64]
  __shared__ __attribute__((aligned(16))) unsigned short Bs[2][2][8192];

  f32x4 acc[8][4];
#pragma unroll
  for (int nt = 0; nt < 4; ++nt) {
    float bv = bias[n0 + wn * 64 + nt * 16 + lr];
    f32x4 bvv = {bv, bv, bv, bv};
#pragma unroll
    for (int mt = 0; mt < 8; ++mt) acc[mt][nt] = bvv;
  }

  const int NT = K >> 6;            // K-tiles of 64

  // stage one half-tile via global_load_lds (dest linear, source pre-swizzled)
  auto stage = [&](int buf, int kt, int isB, int h) {
#pragma unroll
    for (int j = 0; j < 2; ++j) {
      int c   = j * 8 + wid;                         // 1KB chunk 0..15 (wave-uniform)
      int row = c * 8 + (lane >> 3);                 // 0..127
      int col = ((lane & 7) * 8) ^ ((row & 7) << 3); // elems, inverse-swizzled
      const unsigned short* g = isB
          ? &Bw[(n0 + h * 128 + row) * (long)K + kt * 64 + col]
          : &Ab[(m0 + h * 128 + row) * (long)K + kt * 64 + col];
      unsigned short* l = isB ? &Bs[buf][h][c * 512] : &As[buf][h][c * 512];
      GLDS(g, l);
    }
  };

  // ---- AF32 A-path: f32 reg-stage (two named buffers) + cvt + swizzled ds_write ----
  const int ar = tid >> 2, aq = tid & 3;  // row 0..127, col-quarter (16 f32)
  float4 raA[8], raB[8];                  // [h*4 + i] ; rule #20: no runtime idx
  auto issueA = [&](int kt, float4 (&dst)[8]) {
#pragma unroll
    for (int h = 0; h < 2; ++h)
#pragma unroll
      for (int i = 0; i < 4; ++i)
        dst[h * 4 + i] = *(const float4*)&Af[(m0 + h * 128 + ar) * (long)K + kt * 64 + aq * 16 + i * 4];
  };
  auto writeA = [&](int buf, float4 (&src)[8]) {
#pragma unroll
    for (int h = 0; h < 2; ++h) {
#pragma unroll
      for (int s = 0; s < 2; ++s) {
        unsigned int w0 = cvtpk(src[h * 4 + 2 * s].x,     src[h * 4 + 2 * s].y);
        unsigned int w1 = cvtpk(src[h * 4 + 2 * s].z,     src[h * 4 + 2 * s].w);
        unsigned int w2 = cvtpk(src[h * 4 + 2 * s + 1].x, src[h * 4 + 2 * s + 1].y);
        unsigned int w3 = cvtpk(src[h * 4 + 2 * s + 1].z, src[h * 4 + 2 * s + 1].w);
        int col = (aq * 16 + s * 8) ^ ((ar & 7) << 3);   // swizzled elem col
        uint4 pk = {w0, w1, w2, w3};
        *(uint4*)&As[buf][h][ar * 64 + col] = pk;        // ds_write_b128
      }
    }
  };

  // swizzled ds_read of one 16x32 MFMA A/B fragment
  auto ldsA = [&](int buf, int mt, int kk) -> bf16x8 {
    int r = mt * 16 + lr;
    int off = r * 128 + ((kk * 64 + lk * 16) ^ ((lr & 7) << 4));   // bytes
    return *(const bf16x8*)((const char*)&As[buf][wm][0] + off);
  };
  auto ldsB = [&](int buf, int nt, int kk) -> bf16x8 {
    int r = (wn & 1) * 64 + nt * 16 + lr;
    int off = r * 128 + ((kk * 64 + lk * 16) ^ ((lr & 7) << 4));
    return *(const bf16x8*)((const char*)&Bs[buf][wn >> 1][0] + off);
  };

  // ---- prologue ----
  if constexpr (AF32) {
    issueA(0, raB);                         // A(0): iter0's "cur" slot is raB
    stage(0, 0, 1, 0); stage(0, 0, 1, 1);   // B(0)
    writeA(0, raB);                         // compiler reg-dep waits A(0)
    if (NT > 1) issueA(1, raB);             // A(1) -> raB (iter0 cur), after B(0)
    asm volatile("s_waitcnt vmcnt(8) lgkmcnt(0)" ::: "memory");  // B(0) landed; A(1) in flight
  } else {
    stage(0, 0, 0, 0); stage(0, 0, 0, 1); stage(0, 0, 1, 0); stage(0, 0, 1, 1);
    if (NT > 1) {
      stage(1, 1, 0, 0);
      asm volatile("s_waitcnt vmcnt(2)" ::: "memory");
    } else {
      asm volatile("s_waitcnt vmcnt(0)" ::: "memory");
    }
  }
  __builtin_amdgcn_s_barrier();

  for (int u = 0; u < NT; ++u) {
    const int cb = u & 1;
    const bool nx = (u + 1 < NT);
    bf16x8 a[4][2], b0[2][2], b1[2][2];

    if constexpr (AF32) {
      // ---- P1: ds_read A(0-3)+B(0-1); stage B h0 (u+1); MFMA (0-3)x(0-1) ----
#pragma unroll
      for (int mt = 0; mt < 4; ++mt) { a[mt][0] = ldsA(cb, mt, 0); a[mt][1] = ldsA(cb, mt, 1); }
#pragma unroll
      for (int nt = 0; nt < 2; ++nt) { b0[nt][0] = ldsB(cb, nt, 0); b0[nt][1] = ldsB(cb, nt, 1); }
      if (nx) stage(cb ^ 1, u + 1, 1, 0);
      __builtin_amdgcn_s_barrier();
      asm volatile("s_waitcnt lgkmcnt(0)" ::: "memory");
      __builtin_amdgcn_s_setprio(1);
#pragma unroll
      for (int mt = 0; mt < 4; ++mt)
#pragma unroll
        for (int nt = 0; nt < 2; ++nt)
#pragma unroll
          for (int kk = 0; kk < 2; ++kk)
            acc[mt][nt] = __builtin_amdgcn_mfma_f32_16x16x32_bf16(a[mt][kk], b0[nt][kk], acc[mt][nt], 0, 0, 0);
      __builtin_amdgcn_s_setprio(0);
      __builtin_amdgcn_s_barrier();

      // ---- P2: ds_read B(2-3); stage B h1 (u+1); MFMA (0-3)x(2-3) ----
#pragma unroll
      for (int nt = 0; nt < 2; ++nt) { b1[nt][0] = ldsB(cb, 2 + nt, 0); b1[nt][1] = ldsB(cb, 2 + nt, 1); }
      if (nx) stage(cb ^ 1, u + 1, 1, 1);
      __builtin_amdgcn_s_barrier();
      asm volatile("s_waitcnt lgkmcnt(0)" ::: "memory");
      __builtin_amdgcn_s_setprio(1);
#pragma unroll
      for (int mt = 0; mt < 4; ++mt)
#pragma unroll
        for (int nt = 0; nt < 2; ++nt)
#pragma unroll
          for (int kk = 0; kk < 2; ++kk)
            acc[mt][2 + nt] = __builtin_amdgcn_mfma_f32_16x16x32_bf16(a[mt][kk], b1[nt][kk], acc[mt][2 + nt], 0, 0, 0);
      __builtin_amdgcn_s_setprio(0);
      __builtin_amdgcn_s_barrier();

      // ---- P3: ds_read A(4-7); issue A-f32(u+2) into "next" buf; MFMA (4-7)x(2-3) ----
#pragma unroll
      for (int mt = 0; mt < 4; ++mt) { a[mt][0] = ldsA(cb, 4 + mt, 0); a[mt][1] = ldsA(cb, 4 + mt, 1); }
      if (u + 2 < NT) {
        if (u & 1) issueA(u + 2, raB);      // iter odd: next = raB
        else       issueA(u + 2, raA);      // iter even: next = raA
      }
      __builtin_amdgcn_s_barrier();
      asm volatile("s_waitcnt lgkmcnt(0)" ::: "memory");
      __builtin_amdgcn_s_setprio(1);
#pragma unroll
      for (int mt = 0; mt < 4; ++mt)
#pragma unroll
        for (int nt = 0; nt < 2; ++nt)
#pragma unroll
          for (int kk = 0; kk < 2; ++kk)
            acc[4 + mt][2 + nt] = __builtin_amdgcn_mfma_f32_16x16x32_bf16(a[mt][kk], b1[nt][kk], acc[4 + mt][2 + nt], 0, 0, 0);
      __builtin_amdgcn_s_setprio(0);
      __builtin_amdgcn_s_barrier();

      // ---- P4: cvt+ds_write A(u+1) (loaded last iter; reg-dep wait ~free); MFMA (4-7)x(0-1) ----
      if (nx) {
        if (u & 1) writeA(cb ^ 1, raA);     // iter odd: cur = raA
        else       writeA(cb ^ 1, raB);     // iter even: cur = raB
      }
      __builtin_amdgcn_s_barrier();
      __builtin_amdgcn_s_setprio(1);
#pragma unroll
      for (int mt = 0; mt < 4; ++mt)
#pragma unroll
        for (int nt = 0; nt < 2; ++nt)
#pragma unroll
          for (int kk = 0; kk < 2; ++kk)
            acc[4 + mt][nt] = __builtin_amdgcn_mfma_f32_16x16x32_bf16(a[mt][kk], b0[nt][kk], acc[4 + mt][nt], 0, 0, 0);
      __builtin_amdgcn_s_setprio(0);
      // publish BEFORE closing barrier: retire B(u+1) glds + this wave's
      // ds_writes; keep A(u+2) f32 loads (8 newest) in flight.
      if (u + 2 < NT)       asm volatile("s_waitcnt vmcnt(8) lgkmcnt(0)" ::: "memory");
      else if (nx)          asm volatile("s_waitcnt vmcnt(0) lgkmcnt(0)" ::: "memory");
      __builtin_amdgcn_s_barrier();
    } else {
      // ================= round-5 schedule (A bf16 via glds) =================
      // ---- P1 ----
#pragma unroll
      for (int mt = 0; mt < 4; ++mt) { a[mt][0] = ldsA(cb, mt, 0); a[mt][1] = ldsA(cb, mt, 1); }
#pragma unroll
      for (int nt = 0; nt < 2; ++nt) { b0[nt][0] = ldsB(cb, nt, 0); b0[nt][1] = ldsB(cb, nt, 1); }
      if (nx) stage(cb ^ 1, u + 1, 0, 1);
      __builtin_amdgcn_s_barrier();
      asm volatile("s_waitcnt lgkmcnt(0)" ::: "memory");
      __builtin_amdgcn_s_setprio(1);
#pragma unroll
      for (int mt = 0; mt < 4; ++mt)
#pragma unroll
        for (int nt = 0; nt < 2; ++nt)
#pragma unroll
          for (int kk = 0; kk < 2; ++kk)
            acc[mt][nt] = __builtin_amdgcn_mfma_f32_16x16x32_bf16(a[mt][kk], b0[nt][kk], acc[mt][nt], 0, 0, 0);
      __builtin_amdgcn_s_setprio(0);
      __builtin_amdgcn_s_barrier();

      // ---- P2 ----
#pragma unroll
      for (int nt = 0; nt < 2; ++nt) { b1[nt][0] = ldsB(cb, 2 + nt, 0); b1[nt][1] = ldsB(cb, 2 + nt, 1); }
      if (nx) stage(cb ^ 1, u + 1, 1, 0);
      __builtin_amdgcn_s_barrier();
      asm volatile("s_waitcnt lgkmcnt(0)" ::: "memory");
      __builtin_amdgcn_s_setprio(1);
#pragma unroll
      for (int mt = 0; mt < 4; ++mt)
#pragma unroll
        for (int nt = 0; nt < 2; ++nt)
#pragma unroll
          for (int kk = 0; kk < 2; ++kk)
            acc[mt][2 + nt] = __builtin_amdgcn_mfma_f32_16x16x32_bf16(a[mt][kk], b1[nt][kk], acc[mt][2 + nt], 0, 0, 0);
      __builtin_amdgcn_s_setprio(0);
      __builtin_amdgcn_s_barrier();

      // ---- P3 ----
#pragma unroll
      for (int mt = 0; mt < 4; ++mt) { a[mt][0] = ldsA(cb, 4 + mt, 0); a[mt][1] = ldsA(cb, 4 + mt, 1); }
      if (nx) stage(cb ^ 1, u + 1, 1, 1);
      __builtin_amdgcn_s_barrier();
      asm volatile("s_waitcnt lgkmcnt(0)" ::: "memory");
      __builtin_amdgcn_s_setprio(1);
#pragma unroll
      for (int mt = 0; mt < 4; ++mt)
#pragma unroll
        for (int nt = 0; nt < 2; ++nt)
#pragma unroll
          for (int kk = 0; kk < 2; ++kk)
            acc[4 + mt][2 + nt] = __builtin_amdgcn_mfma_f32_16x16x32_bf16(a[mt][kk], b1[nt][kk], acc[4 + mt][2 + nt], 0, 0, 0);
      __builtin_amdgcn_s_setprio(0);
      __builtin_amdgcn_s_barrier();

      // ---- P4 ----
      if (u + 2 < NT) stage(cb, u + 2, 0, 0);
      __builtin_amdgcn_s_barrier();
      __builtin_amdgcn_s_setprio(1);
#pragma unroll
      for (int mt = 0; mt < 4; ++mt)
#pragma unroll
        for (int nt = 0; nt < 2; ++nt)
#pragma unroll
          for (int kk = 0; kk < 2; ++kk)
            acc[4 + mt][nt] = __builtin_amdgcn_mfma_f32_16x16x32_bf16(a[mt][kk], b0[nt][kk], acc[4 + mt][nt], 0, 0, 0);
      __builtin_amdgcn_s_setprio(0);
      if (u + 2 < NT)       asm volatile("s_waitcnt vmcnt(2)" ::: "memory");
      else if (u + 1 < NT)  asm volatile("s_waitcnt vmcnt(0)" ::: "memory");
      __builtin_amdgcn_s_barrier();
    }
  }

  // ---- epilogue ----
#pragma unroll
  for (int mt = 0; mt < 8; ++mt)
#pragma unroll
    for (int nt = 0; nt < 4; ++nt) {
      long col = n0 + wn * 64 + nt * 16 + lr;
#pragma unroll
      for (int r = 0; r < 4; ++r) {
        long row = m0 + wm * 128 + mt * 16 + lk * 4 + r;
        float v = acc[mt][nt][r];
        if constexpr (sizeof(OutT) == 4) C[row * Nn + col] = v;
        else                             C[row * Nn + col] = f2b(v);
      }
    }
}

// ---------------- attention, coalesced ----------------
__global__ __launch_bounds__(512) void k_attn(const unsigned short* __restrict__ kv,
                                              const unsigned short* __restrict__ qx,
                                              const unsigned short* __restrict__ qp,
                                              unsigned short* __restrict__ o) {
  __shared__ unsigned short Ks[32 * 772];
  __shared__ unsigned short Qs[6 * 768];
  __shared__ float Ss[120 * 16];
  const int tid = threadIdx.x;
  const long p0 = (long)blockIdx.x * 2;

  for (int i = tid; i < 32 * 96; i += 512) {
    int r = i / 96, c8 = i - (i / 96) * 96;
    u16x8 vv = *(const u16x8*)&kv[((p0 + (r >> 4)) * 16 + (r & 15)) * 1536 + c8 * 8];
    *(u16x8*)&Ks[r * 772 + c8 * 8] = vv;
  }
  for (int i = tid; i < 6 * 96; i += 512) {
    int r = i / 96, c8 = i - (i / 96) * 96;
    const unsigned short* src = (r < 2) ? &qx[(p0 + r) * 768 + c8 * 8]
                                        : &qp[(long)(r - 2) * 768 + c8 * 8];
    *(u16x8*)&Qs[r * 768 + c8 * 8] = *(const u16x8*)src;
  }
  __syncthreads();

  for (int idx = tid; idx < 1920; idx += 512) {
    int w = idx & 15, rest = idx >> 4;
    int h = rest % 12, pq = rest / 12;
    int q5 = pq % 5, p = pq / 5;
    const unsigned short* krow = &Ks[(p * 16 + w) * 772 + h * 64];
    const unsigned short* qrow = &Qs[((q5 == 0) ? p : 1 + q5) * 768 + h * 64];
    float s = 0.f;
#pragma unroll
    for (int j = 0; j < 8; ++j) {
      u16x8 kk = *(const u16x8*)&krow[j * 8];
      u16x8 qq = *(const u16x8*)&qrow[j * 8];
#pragma unroll
      for (int e = 0; e < 8; ++e) s += bf2f(qq[e]) * bf2f(kk[e]);
    }
    s *= 0.125f;
    float m = s;
#pragma unroll
    for (int d = 1; d < 16; d <<= 1) m = fmaxf(m, __shfl_xor(m, d));
    float e = __expf(s - m);
    float sum = e;
#pragma unroll
    for (int d = 1; d < 16; d <<= 1) sum += __shfl_xor(sum, d);
    Ss[rest * 16 + w] = e / sum;
  }
  __syncthreads();

  for (int idx = tid; idx < 960; idx += 512) {
    int d8 = idx % 96, pq = idx / 96;
    int q5 = pq % 5, p = pq / 5, h = d8 >> 3;
    const float* arow = &Ss[(pq * 12 + h) * 16];
    const unsigned short* vbase = &kv[(p0 + p) * 16 * 1536 + 768 + d8 * 8];
    float acc[8] = {0.f,0.f,0.f,0.f,0.f,0.f,0.f,0.f};
#pragma unroll
    for (int w = 0; w < 16; ++w) {
      u16x8 vv = *(const u16x8*)&vbase[(long)w * 1536];
      float aw = arow[w];
#pragma unroll
      for (int e = 0; e < 8; ++e) acc[e] += aw * bf2f(vv[e]);
    }
    u16x8 ov;
#pragma unroll
    for (int e = 0; e < 8; ++e) ov[e] = f2b(acc[e]);
    *(u16x8*)&o[((p0 + p) * 5 + q5) * 768 + d8 * 8] = ov;
  }
}

// ---------------------------------------------------------------------------
extern "C" void kernel_launch(void* const* d_in, const int* in_sizes, int n_in,
                              void* d_out, int out_size, void* d_ws, size_t ws_size,
                              hipStream_t stream) {
  const float* x      = (const float*)d_in[0];   // [32,576,1536]
  const float* y      = (const float*)d_in[1];   // [32,9216,1024]
  const float* Wx     = (const float*)d_in[2];   // [768,1536]
  const float* bx     = (const float*)d_in[3];   // [768]
  const float* Wy     = (const float*)d_in[4];   // [768,1024]
  const float* by     = (const float*)d_in[5];   // [768]
  const float* prompt = (const float*)d_in[6];   // [1,4,768]
  const float* ipw    = (const float*)d_in[7];   // [2304,768]
  const float* ipb    = (const float*)d_in[8];   // [2304]
  const float* outw   = (const float*)d_in[9];   // [768,768]
  const float* outb   = (const float*)d_in[10];  // [768]
  float* out = (float*)d_out;

  char* ws = (char*)d_ws;
  size_t off = 0;
  auto alloc = [&](size_t bytes) -> void* {
    void* p = ws + off; off += (bytes + 255) & ~(size_t)255; return p;
  };
  unsigned short* kvb  = (unsigned short*)alloc(294912UL * 1536 * 2);  // 906 MB
  unsigned short* qxb  = (unsigned short*)alloc(18432UL * 768 * 2);    // 28 MB
  unsigned short* ob   = (unsigned short*)alloc(92160UL * 768 * 2);    // 142 MB
  unsigned short* Wqx  = (unsigned short*)alloc(768UL * 1536 * 2);
  unsigned short* Wkv  = (unsigned short*)alloc(1536UL * 1024 * 2);
  unsigned short* oww  = (unsigned short*)alloc(768UL * 768 * 2);
  unsigned short* qpf  = (unsigned short*)alloc(4UL * 768 * 2);
  float*          bqx  = (float*)alloc(768 * 4);
  float*          bkv  = (float*)alloc(1536 * 4);
  unsigned short* xb   = ob;  // alias (dead before k_attn writes ob)

  // ---- weight prep ----
  k_cvt<<<dim3(288), dim3(256), 0, stream>>>(outw, oww, 768L * 768 / 8);
  k_wfuse<<<dim3(6, 96), dim3(256), 0, stream>>>(ipw,              Wx, Wqx,              768, 768, 1536);
  k_wfuse<<<dim3(4, 96), dim3(256), 0, stream>>>(ipw + 768 * 768,  Wy, Wkv,              768, 768, 1024);
  k_wfuse<<<dim3(4, 96), dim3(256), 0, stream>>>(ipw + 1536 * 768, Wy, Wkv + 768 * 1024, 768, 768, 1024);
  k_bfuse<<<dim3(576), dim3(256), 0, stream>>>(ipw, ipb, bx, by, bqx, bkv);
  k_qprompt<<<dim3(768), dim3(256), 0, stream>>>(ipw, ipb, prompt, qpf);

  // ---- x -> bf16; q_x = xb @ Wqx^T + bqx  (M=18432, N=768, K=1536) ----
  k_cvt<<<dim3(2048), dim3(256), 0, stream>>>(x, xb, 18432L * 1536 / 8);
  k_gemm<unsigned short><<<dim3(144 * 6), dim3(256), 0, stream>>>(
      xb, Wqx, bqx, qxb, 18432, 768, 1536, 6);

  // ---- kv = y_f32 @ Wkv^T + bkv  (M=294912, N=1536, K=1024), cvt fused ----
  k_gemm8<true, unsigned short><<<dim3(1152 * 6), dim3(512), 0, stream>>>(
      (const void*)y, Wkv, bkv, kvb, 294912, 1536, 1024, 6);

  // ---- attention -> o bf16 ----
  k_attn<<<dim3(9216), dim3(512), 0, stream>>>(kvb, qxb, qpf, ob);

  // ---- out = o @ oww^T + outb  (M=92160, N=768, K=768) -> f32, 8-phase ----
  k_gemm8<false, float><<<dim3(360 * 3), dim3(512), 0, stream>>>(
      (const void*)ob, oww, outb, out, 92160, 768, 768, 3);
}

// Round 9
// 2528.708 us; speedup vs baseline: 2.9462x; 2.9454x over previous
//
#include <hip/hip_runtime.h>
#include <hip/hip_bf16.h>

// ---------------------------------------------------------------------------
// LocalizedPromptedAttentionLayer on MI355X (gfx950) — round 9
// B=32, N=576 patches, W=16 kv-window, d=768, P=4 prompts, H=12 heads, Dh=64
//
//   xb   = bf16(x)                                [18432, 1536]  (aliased in ob)
//   q_x  = xb @ (Wq@Wx)^T + (bq + Wq@bx)          [18432, 768] bf16   (128² GEMM)
//   qprm = prompt @ Wq^T + bq                     [4, 768] bf16
//   yb   = bf16(y)  (chunked vs ws_size)          [rows, 1024]
//   kv   = yb @ [Wk@Wy ; Wv@Wy]^T + bias          [294912, 1536] bf16 (256² 8-phase)
//   o    = softmax(q k^T / 8) v                   [92160, 768] bf16
//   out  = o @ out_w^T + out_b                    [92160, 768] f32    (256² 8-phase)
//
// Round-9 vs round 5 (r7/r8 reg-staged fusion reverted — it spilled):
//   * k_attn: 16B-aligned LDS rows (stride 776, was 772 -> misaligned b128),
//     Q staged as f32, packed v_pk_fma_f32 dots, v_cvt_pk_bf16_f32 output.
//   * weight fusion (Wq@Wx etc) via MFMA GEMMs instead of broadcast-load
//     k_wfuse (was VMEM-issue bound, ~250 us): cvt ipw->bf16, transpose
//     Wx/Wy to bf16, zero-bias 128² GEMMs.
// ---------------------------------------------------------------------------

typedef __attribute__((ext_vector_type(8))) short bf16x8;   // MFMA A/B frag
typedef __attribute__((ext_vector_type(4))) float f32x4;    // MFMA C/D frag
typedef __attribute__((ext_vector_type(2))) float f32x2;
typedef __attribute__((ext_vector_type(8))) unsigned short u16x8;

__device__ __forceinline__ float bf2f(unsigned short u) {
  union { unsigned int i; float f; } x; x.i = ((unsigned int)u) << 16; return x.f;
}
__device__ __forceinline__ unsigned short f2b(float f) {
  union { float f; unsigned int i; } x; x.f = f;
  unsigned int u = x.i;
  return (unsigned short)((u + 0x7fffu + ((u >> 16) & 1u)) >> 16);  // RNE
}
__device__ __forceinline__ unsigned int cvtpk(float lo, float hi) {
  unsigned int r;
  asm("v_cvt_pk_bf16_f32 %0, %1, %2" : "=v"(r) : "v"(lo), "v"(hi));  // RNE pack
  return r;
}
// expand packed bf16 pair (one u32) to f32x2: lo = u<<16, hi = u&0xFFFF0000
__device__ __forceinline__ f32x2 bf2x(unsigned int u) {
  union { unsigned int i; float f; } lo, hi;
  lo.i = u << 16; hi.i = u & 0xFFFF0000u;
  f32x2 r; r[0] = lo.f; r[1] = hi.f; return r;
}
__device__ __forceinline__ void pkfma(f32x2& acc, f32x2 a, f32x2 b) {
  asm("v_pk_fma_f32 %0, %1, %2, %0" : "+v"(acc) : "v"(a), "v"(b));
}

#define GLDS(gaddr, laddr) \
  __builtin_amdgcn_global_load_lds( \
      (const __attribute__((address_space(1))) unsigned int*)(gaddr), \
      (__attribute__((address_space(3))) unsigned int*)(laddr), 16, 0, 0)

// ---------------- f32 -> bf16 bulk convert (8 elems/thread-iter) ----------------
__global__ void k_cvt(const float* __restrict__ src, unsigned short* __restrict__ dst, long n8) {
  long stride = (long)gridDim.x * blockDim.x;
  for (long i = (long)blockIdx.x * blockDim.x + threadIdx.x; i < n8; i += stride) {
    float4 a = ((const float4*)src)[2 * i];
    float4 b = ((const float4*)src)[2 * i + 1];
    u16x8 t = { f2b(a.x), f2b(a.y), f2b(a.z), f2b(a.w),
                f2b(b.x), f2b(b.y), f2b(b.z), f2b(b.w) };
    ((u16x8*)dst)[i] = t;
  }
}

// ---------------- tiled transpose: src[R][C] f32 -> dst[C][R] bf16 ----------------
__global__ __launch_bounds__(256) void k_tr(const float* __restrict__ src,
                                            unsigned short* __restrict__ dst,
                                            int R, int C) {
  __shared__ float t[32][33];
  int bx = blockIdx.x * 32, by = blockIdx.y * 32;
  int lx = threadIdx.x & 31, ly = threadIdx.x >> 5;   // 32 x 8
#pragma unroll
  for (int s = 0; s < 32; s += 8)
    t[ly + s][lx] = src[(long)(by + ly + s) * C + bx + lx];
  __syncthreads();
#pragma unroll
  for (int s = 0; s < 32; s += 8)
    dst[(long)(bx + ly + s) * R + by + lx] = f2b(t[lx][ly + s]);
}

// ---------------- zero fill ----------------
__global__ void k_zf(float* __restrict__ p, int n) {
  int i = blockIdx.x * 256 + threadIdx.x;
  if (i < n) p[i] = 0.f;
}

// ---------------- fused biases ----------------
__global__ void k_bfuse(const float* __restrict__ ipw, const float* __restrict__ ipb,
                        const float* __restrict__ bx, const float* __restrict__ by,
                        float* __restrict__ bqx, float* __restrict__ bkv) {
  int o    = blockIdx.x * 4 + (threadIdx.x >> 6);   // 0..2303 (grid 576)
  int lane = threadIdx.x & 63;
  int sec  = o / 768, jj = o - sec * 768;
  const float* Arow = ipw + (long)o * 768;
  const float* vb   = (sec == 0) ? bx : by;
  float s = 0.f;
  for (int k = lane; k < 768; k += 64) s += Arow[k] * vb[k];
#pragma unroll
  for (int d = 32; d > 0; d >>= 1) s += __shfl_down(s, d);
  if (lane == 0) {
    s += ipb[o];
    if (sec == 0) bqx[jj] = s;
    else if (sec == 1) bkv[jj] = s;
    else bkv[768 + jj] = s;
  }
}

// ---------------- prompt queries ----------------
__global__ void k_qprompt(const float* __restrict__ ipw, const float* __restrict__ ipb,
                          const float* __restrict__ prompt, unsigned short* __restrict__ qpf) {
  int o    = blockIdx.x * 4 + (threadIdx.x >> 6);   // 0..3071 (grid 768)
  int lane = threadIdx.x & 63;
  int p = o / 768, j = o - p * 768;
  const float* Wqr = ipw + (long)j * 768;
  const float* pr  = prompt + (long)p * 768;
  float s = 0.f;
  for (int k = lane; k < 768; k += 64) s += Wqr[k] * pr[k];
#pragma unroll
  for (int d = 32; d > 0; d >>= 1) s += __shfl_down(s, d);
  if (lane == 0) qpf[o] = f2b(s + ipb[j]);
}

// ---------------- 128² GEMM (proven m97 structure) ----------------
template <typename OutT>
__global__ __launch_bounds__(256) void k_gemm(const unsigned short* __restrict__ A,
                                              const unsigned short* __restrict__ Bw,
                                              const float* __restrict__ bias,
                                              OutT* __restrict__ C,
                                              int M, int Nn, int K, int nbx) {
  const int tid  = threadIdx.x;
  const int lane = tid & 63, wid = tid >> 6;
  const int wm = wid >> 1, wn = wid & 1;
  const int lr = lane & 15, lk = lane >> 4;

  const int nwg = gridDim.x, orig = blockIdx.x;
  const int q8 = nwg >> 3, r8 = nwg & 7, xc = orig & 7;
  const int wg = (xc < r8 ? xc * (q8 + 1) : r8 * (q8 + 1) + (xc - r8) * q8) + (orig >> 3);
  const int bn = wg % nbx, bm = wg / nbx;
  const int m0 = bm * 128, n0 = bn * 128;

  __shared__ __attribute__((aligned(16))) unsigned short As[2][128 * 32];
  __shared__ __attribute__((aligned(16))) unsigned short Bs[2][128 * 32];

  f32x4 acc[4][4];
#pragma unroll
  for (int nt = 0; nt < 4; ++nt) {
    float bv = bias[n0 + wn * 64 + nt * 16 + lr];
    f32x4 bvv = {bv, bv, bv, bv};
#pragma unroll
    for (int mt = 0; mt < 4; ++mt) acc[mt][nt] = bvv;
  }

  const int NS = K >> 5;
  const int crow = lane >> 2, ck8 = (lane & 3) * 8;

  auto stage = [&](int buf, int ks) {
#pragma unroll
    for (int i = 0; i < 2; ++i) {
      int c = wid * 2 + i;
      int row = c * 16 + crow;
      GLDS(&A[(long)(m0 + row) * K + ks * 32 + ck8], &As[buf][c * 512]);
      GLDS(&Bw[(long)(n0 + row) * K + ks * 32 + ck8], &Bs[buf][c * 512]);
    }
  };

  stage(0, 0);
  __syncthreads();

  for (int t = 0; t < NS; ++t) {
    const int cur = t & 1, nb = cur ^ 1;
    if (t + 1 < NS) stage(nb, t + 1);
    bf16x8 af[4], bfr[4];
#pragma unroll
    for (int mt = 0; mt < 4; ++mt)
      af[mt] = *(const bf16x8*)&As[cur][(wm * 64 + mt * 16 + lr) * 32 + lk * 8];
#pragma unroll
    for (int nt = 0; nt < 4; ++nt)
      bfr[nt] = *(const bf16x8*)&Bs[cur][(wn * 64 + nt * 16 + lr) * 32 + lk * 8];
#pragma unroll
    for (int mt = 0; mt < 4; ++mt)
#pragma unroll
      for (int nt = 0; nt < 4; ++nt)
        acc[mt][nt] = __builtin_amdgcn_mfma_f32_16x16x32_bf16(af[mt], bfr[nt], acc[mt][nt], 0, 0, 0);
    __syncthreads();
  }

#pragma unroll
  for (int mt = 0; mt < 4; ++mt)
#pragma unroll
    for (int nt = 0; nt < 4; ++nt) {
      int col = n0 + wn * 64 + nt * 16 + lr;
#pragma unroll
      for (int r = 0; r < 4; ++r) {
        int row = m0 + wm * 64 + mt * 16 + lk * 4 + r;
        float v = acc[mt][nt][r];
        if constexpr (sizeof(OutT) == 4) C[(long)row * Nn + col] = v;
        else                             C[(long)row * Nn + col] = f2b(v);
      }
    }
}

// ---------------- 256² 8-phase GEMM (round-5 proven schedule) ----------------
template <typename OutT>
__global__ __launch_bounds__(512, 2) void k_gemm8(const unsigned short* __restrict__ A,
                                                  const unsigned short* __restrict__ Bw,
                                                  const float* __restrict__ bias,
                                                  OutT* __restrict__ C,
                                                  int M, int Nn, int K, int nbx) {
  const int tid  = threadIdx.x;
  const int lane = tid & 63, wid = tid >> 6;
  const int wm = wid >> 2, wn = wid & 3;          // 2 x 4 waves
  const int lr = lane & 15, lk = lane >> 4;

  const int nwg = gridDim.x, orig = blockIdx.x;
  const int q8 = nwg >> 3, r8 = nwg & 7, xc = orig & 7;
  const int wg = (xc < r8 ? xc * (q8 + 1) : r8 * (q8 + 1) + (xc - r8) * q8) + (orig >> 3);
  const int bn = wg % nbx, bm = wg / nbx;
  const long m0 = (long)bm * 256, n0 = (long)bn * 256;

  __shared__ __attribute__((aligned(16))) unsigned short As[2][2][8192];  // [buf][half][128*64]
  __shared__ __attribute__((aligned(16))) unsigned short Bs[2][2][8192];

  f32x4 acc[8][4];
#pragma unroll
  for (int nt = 0; nt < 4; ++nt) {
    float bv = bias[n0 + wn * 64 + nt * 16 + lr];
    f32x4 bvv = {bv, bv, bv, bv};
#pragma unroll
    for (int mt = 0; mt < 8; ++mt) acc[mt][nt] = bvv;
  }

  const int NT = K >> 6;            // K-tiles of 64

  auto stage = [&](int buf, int kt, int isB, int h) {
#pragma unroll
    for (int j = 0; j < 2; ++j) {
      int c   = j * 8 + wid;                         // 1KB chunk (wave-uniform)
      int row = c * 8 + (lane >> 3);                 // 0..127
      int col = ((lane & 7) * 8) ^ ((row & 7) << 3); // elems, inverse-swizzled
      const unsigned short* g = isB
          ? &Bw[(n0 + h * 128 + row) * (long)K + kt * 64 + col]
          : &A [(m0 + h * 128 + row) * (long)K + kt * 64 + col];
      unsigned short* l = isB ? &Bs[buf][h][c * 512] : &As[buf][h][c * 512];
      GLDS(g, l);
    }
  };
  auto ldsA = [&](int buf, int mt, int kk) -> bf16x8 {
    int r = mt * 16 + lr;
    int off = r * 128 + ((kk * 64 + lk * 16) ^ ((lr & 7) << 4));   // bytes
    return *(const bf16x8*)((const char*)&As[buf][wm][0] + off);
  };
  auto ldsB = [&](int buf, int nt, int kk) -> bf16x8 {
    int r = (wn & 1) * 64 + nt * 16 + lr;
    int off = r * 128 + ((kk * 64 + lk * 16) ^ ((lr & 7) << 4));
    return *(const bf16x8*)((const char*)&Bs[buf][wn >> 1][0] + off);
  };

  // ---- prologue: tile0 (all 4 halves) + tile1 A-half0 ----
  stage(0, 0, 0, 0); stage(0, 0, 0, 1); stage(0, 0, 1, 0); stage(0, 0, 1, 1);
  if (NT > 1) {
    stage(1, 1, 0, 0);
    asm volatile("s_waitcnt vmcnt(2)" ::: "memory");
  } else {
    asm volatile("s_waitcnt vmcnt(0)" ::: "memory");
  }
  __builtin_amdgcn_s_barrier();

  for (int u = 0; u < NT; ++u) {
    const int cb = u & 1;
    bf16x8 a[4][2], b0[2][2], b1[2][2];

    // ---- P1 ----
#pragma unroll
    for (int mt = 0; mt < 4; ++mt) { a[mt][0] = ldsA(cb, mt, 0); a[mt][1] = ldsA(cb, mt, 1); }
#pragma unroll
    for (int nt = 0; nt < 2; ++nt) { b0[nt][0] = ldsB(cb, nt, 0); b0[nt][1] = ldsB(cb, nt, 1); }
    if (u + 1 < NT) stage(cb ^ 1, u + 1, 0, 1);
    __builtin_amdgcn_s_barrier();
    asm volatile("s_waitcnt lgkmcnt(0)" ::: "memory");
    __builtin_amdgcn_s_setprio(1);
#pragma unroll
    for (int mt = 0; mt < 4; ++mt)
#pragma unroll
      for (int nt = 0; nt < 2; ++nt)
#pragma unroll
        for (int kk = 0; kk < 2; ++kk)
          acc[mt][nt] = __builtin_amdgcn_mfma_f32_16x16x32_bf16(a[mt][kk], b0[nt][kk], acc[mt][nt], 0, 0, 0);
    __builtin_amdgcn_s_setprio(0);
    __builtin_amdgcn_s_barrier();

    // ---- P2 ----
#pragma unroll
    for (int nt = 0; nt < 2; ++nt) { b1[nt][0] = ldsB(cb, 2 + nt, 0); b1[nt][1] = ldsB(cb, 2 + nt, 1); }
    if (u + 1 < NT) stage(cb ^ 1, u + 1, 1, 0);
    __builtin_amdgcn_s_barrier();
    asm volatile("s_waitcnt lgkmcnt(0)" ::: "memory");
    __builtin_amdgcn_s_setprio(1);
#pragma unroll
    for (int mt = 0; mt < 4; ++mt)
#pragma unroll
      for (int nt = 0; nt < 2; ++nt)
#pragma unroll
        for (int kk = 0; kk < 2; ++kk)
          acc[mt][2 + nt] = __builtin_amdgcn_mfma_f32_16x16x32_bf16(a[mt][kk], b1[nt][kk], acc[mt][2 + nt], 0, 0, 0);
    __builtin_amdgcn_s_setprio(0);
    __builtin_amdgcn_s_barrier();

    // ---- P3 ----
#pragma unroll
    for (int mt = 0; mt < 4; ++mt) { a[mt][0] = ldsA(cb, 4 + mt, 0); a[mt][1] = ldsA(cb, 4 + mt, 1); }
    if (u + 1 < NT) stage(cb ^ 1, u + 1, 1, 1);
    __builtin_amdgcn_s_barrier();
    asm volatile("s_waitcnt lgkmcnt(0)" ::: "memory");
    __builtin_amdgcn_s_setprio(1);
#pragma unroll
    for (int mt = 0; mt < 4; ++mt)
#pragma unroll
      for (int nt = 0; nt < 2; ++nt)
#pragma unroll
        for (int kk = 0; kk < 2; ++kk)
          acc[4 + mt][2 + nt] = __builtin_amdgcn_mfma_f32_16x16x32_bf16(a[mt][kk], b1[nt][kk], acc[4 + mt][2 + nt], 0, 0, 0);
    __builtin_amdgcn_s_setprio(0);
    __builtin_amdgcn_s_barrier();

    // ---- P4 ----
    if (u + 2 < NT) stage(cb, u + 2, 0, 0);
    __builtin_amdgcn_s_barrier();
    __builtin_amdgcn_s_setprio(1);
#pragma unroll
    for (int mt = 0; mt < 4; ++mt)
#pragma unroll
      for (int nt = 0; nt < 2; ++nt)
#pragma unroll
        for (int kk = 0; kk < 2; ++kk)
          acc[4 + mt][nt] = __builtin_amdgcn_mfma_f32_16x16x32_bf16(a[mt][kk], b0[nt][kk], acc[4 + mt][nt], 0, 0, 0);
    __builtin_amdgcn_s_setprio(0);
    // counted drain BEFORE the closing barrier (cross-wave publish, r5 rule)
    if (u + 2 < NT)       asm volatile("s_waitcnt vmcnt(2)" ::: "memory");
    else if (u + 1 < NT)  asm volatile("s_waitcnt vmcnt(0)" ::: "memory");
    __builtin_amdgcn_s_barrier();
  }

  // ---- epilogue ----
#pragma unroll
  for (int mt = 0; mt < 8; ++mt)
#pragma unroll
    for (int nt = 0; nt < 4; ++nt) {
      long col = n0 + wn * 64 + nt * 16 + lr;
#pragma unroll
      for (int r = 0; r < 4; ++r) {
        long row = m0 + wm * 128 + mt * 16 + lk * 4 + r;
        float v = acc[mt][nt][r];
        if constexpr (sizeof(OutT) == 4) C[row * Nn + col] = v;
        else                             C[row * Nn + col] = f2b(v);
      }
    }
}

// ---------------- attention: aligned LDS + packed f32 math ----------------
// 1 block = 2 patches, 512 thr. Ks row stride 776 elems (1552 B, 16B-aligned
// b128). Q staged f32. Dots via v_pk_fma_f32 (2 MACs/instr), bf16 pair
// expand = 2 VALU. Output packed with v_cvt_pk_bf16_f32.
__global__ __launch_bounds__(512) void k_attn(const unsigned short* __restrict__ kv,
                                              const unsigned short* __restrict__ qx,
                                              const unsigned short* __restrict__ qp,
                                              unsigned short* __restrict__ o) {
  __shared__ __attribute__((aligned(16))) unsigned short Ks[32 * 776];
  __shared__ __attribute__((aligned(16))) float Qsf[6 * 768];
  __shared__ float Ss[120 * 16];
  const int tid = threadIdx.x;
  const long p0 = (long)blockIdx.x * 2;

  // stage K (k-half of kv rows): coalesced 16B chunks
  for (int i = tid; i < 32 * 96; i += 512) {
    int r = i / 96, c8 = i - (i / 96) * 96;
    *(u16x8*)&Ks[r * 776 + c8 * 8] =
        *(const u16x8*)&kv[((p0 + (r >> 4)) * 16 + (r & 15)) * 1536 + c8 * 8];
  }
  // stage Q as f32
  for (int i = tid; i < 6 * 96; i += 512) {
    int r = i / 96, c8 = i - (i / 96) * 96;
    const unsigned short* src = (r < 2) ? &qx[(p0 + r) * 768 + c8 * 8]
                                        : &qp[(long)(r - 2) * 768 + c8 * 8];
    u16x8 v = *(const u16x8*)src;
    float* dst = &Qsf[r * 768 + c8 * 8];
#pragma unroll
    for (int e = 0; e < 8; ++e) dst[e] = bf2f(v[e]);
  }
  __syncthreads();

  // scores + softmax: 2p x 5q x 12h x 16w = 1920 items (16-lane w-groups)
  for (int idx = tid; idx < 1920; idx += 512) {
    int w = idx & 15, rest = idx >> 4;
    int h = rest % 12, pq = rest / 12;
    int q5 = pq % 5, p = pq / 5;
    const unsigned int* kr = (const unsigned int*)&Ks[(p * 16 + w) * 776 + h * 64];
    const float* qr = &Qsf[((q5 == 0) ? p : 1 + q5) * 768 + h * 64];
    f32x2 a2 = {0.f, 0.f};
#pragma unroll
    for (int j = 0; j < 8; ++j) {
      uint4  kw = *(const uint4*)(kr + j * 4);
      float4 q0 = *(const float4*)(qr + j * 8);
      float4 q1 = *(const float4*)(qr + j * 8 + 4);
      f32x2 q01 = {q0.x, q0.y}, q23 = {q0.z, q0.w};
      f32x2 q45 = {q1.x, q1.y}, q67 = {q1.z, q1.w};
      pkfma(a2, bf2x(kw.x), q01);
      pkfma(a2, bf2x(kw.y), q23);
      pkfma(a2, bf2x(kw.z), q45);
      pkfma(a2, bf2x(kw.w), q67);
    }
    float s = (a2[0] + a2[1]) * 0.125f;
    float m = s;
#pragma unroll
    for (int d = 1; d < 16; d <<= 1) m = fmaxf(m, __shfl_xor(m, d));
    float e = __expf(s - m);
    float sum = e;
#pragma unroll
    for (int d = 1; d < 16; d <<= 1) sum += __shfl_xor(sum, d);
    Ss[rest * 16 + w] = e / sum;
  }
  __syncthreads();

  // PV: 10 pq-rows x 96 d8-chunks; 8 outputs/lane, packed FMA pairs
  for (int idx = tid; idx < 960; idx += 512) {
    int d8 = idx % 96, pq = idx / 96;
    int q5 = pq % 5, p = pq / 5, h = d8 >> 3;
    const float* arow = &Ss[(pq * 12 + h) * 16];
    const unsigned short* vbase = &kv[(p0 + p) * 16 * 1536 + 768 + d8 * 8];
    f32x2 a0 = {0.f, 0.f}, a1 = {0.f, 0.f}, a2v = {0.f, 0.f}, a3 = {0.f, 0.f};
#pragma unroll
    for (int w = 0; w < 16; ++w) {
      uint4 vv = *(const uint4*)&vbase[(long)w * 1536];
      float aw = arow[w];
      f32x2 aw2 = {aw, aw};
      pkfma(a0,  bf2x(vv.x), aw2);
      pkfma(a1,  bf2x(vv.y), aw2);
      pkfma(a2v, bf2x(vv.z), aw2);
      pkfma(a3,  bf2x(vv.w), aw2);
    }
    uint4 pk;
    pk.x = cvtpk(a0[0],  a0[1]);
    pk.y = cvtpk(a1[0],  a1[1]);
    pk.z = cvtpk(a2v[0], a2v[1]);
    pk.w = cvtpk(a3[0],  a3[1]);
    *(uint4*)&o[((p0 + p) * 5 + q5) * 768 + d8 * 8] = pk;
  }
}

// ---------------------------------------------------------------------------
extern "C" void kernel_launch(void* const* d_in, const int* in_sizes, int n_in,
                              void* d_out, int out_size, void* d_ws, size_t ws_size,
                              hipStream_t stream) {
  const float* x      = (const float*)d_in[0];   // [32,576,1536]
  const float* y      = (const float*)d_in[1];   // [32,9216,1024]
  const float* Wx     = (const float*)d_in[2];   // [768,1536]
  const float* bx     = (const float*)d_in[3];   // [768]
  const float* Wy     = (const float*)d_in[4];   // [768,1024]
  const float* by     = (const float*)d_in[5];   // [768]
  const float* prompt = (const float*)d_in[6];   // [1,4,768]
  const float* ipw    = (const float*)d_in[7];   // [2304,768]
  const float* ipb    = (const float*)d_in[8];   // [2304]
  const float* outw   = (const float*)d_in[9];   // [768,768]
  const float* outb   = (const float*)d_in[10];  // [768]
  float* out = (float*)d_out;

  char* ws = (char*)d_ws;
  size_t off = 0;
  auto alloc = [&](size_t bytes) -> void* {
    void* p = ws + off; off += (bytes + 255) & ~(size_t)255; return p;
  };
  unsigned short* kvb  = (unsigned short*)alloc(294912UL * 1536 * 2);  // 906 MB
  unsigned short* qxb  = (unsigned short*)alloc(18432UL * 768 * 2);    // 28 MB
  unsigned short* ob   = (unsigned short*)alloc(92160UL * 768 * 2);    // 142 MB
  unsigned short* Wqx  = (unsigned short*)alloc(768UL * 1536 * 2);
  unsigned short* Wkv  = (unsigned short*)alloc(1536UL * 1024 * 2);
  unsigned short* oww  = (unsigned short*)alloc(768UL * 768 * 2);
  unsigned short* qpf  = (unsigned short*)alloc(4UL * 768 * 2);
  float*          bqx  = (float*)alloc(768 * 4);
  float*          bkv  = (float*)alloc(1536 * 4);
  unsigned short* ipwb = (unsigned short*)alloc(2304UL * 768 * 2);     // bf16 in_proj_w
  unsigned short* WxT  = (unsigned short*)alloc(1536UL * 768 * 2);     // Wx^T bf16
  unsigned short* WyT  = (unsigned short*)alloc(1024UL * 768 * 2);     // Wy^T bf16
  float*          zb   = (float*)alloc(1536 * 4);                      // zero bias
  unsigned short* xb   = ob;  // alias (dead before k_attn writes ob)
  unsigned short* ybc  = (unsigned short*)(ws + off);
  long rpc = (long)((ws_size - off) / (1024 * 2)) & ~255L;  // rows/chunk, mult of 256
  if (rpc > 294912) rpc = 294912;
  if (rpc < 256) rpc = 256;

  // ---- weight prep ----
  k_cvt<<<dim3(288), dim3(256), 0, stream>>>(outw, oww, 768L * 768 / 8);
  k_cvt<<<dim3(864), dim3(256), 0, stream>>>(ipw, ipwb, 2304L * 768 / 8);
  k_tr<<<dim3(48, 24), dim3(256), 0, stream>>>(Wx, WxT, 768, 1536);
  k_tr<<<dim3(32, 24), dim3(256), 0, stream>>>(Wy, WyT, 768, 1024);
  k_zf<<<dim3(6), dim3(256), 0, stream>>>(zb, 1536);
  // fused weights via MFMA GEMM: Wqx = Wq @ Wx  (M=768, N=1536, K=768)
  k_gemm<unsigned short><<<dim3(6 * 12), dim3(256), 0, stream>>>(
      ipwb, WxT, zb, Wqx, 768, 1536, 768, 12);
  // Wk@Wy, Wv@Wy  (M=768, N=1024, K=768)
  k_gemm<unsigned short><<<dim3(6 * 8), dim3(256), 0, stream>>>(
      ipwb + 768 * 768, WyT, zb, Wkv, 768, 1024, 768, 8);
  k_gemm<unsigned short><<<dim3(6 * 8), dim3(256), 0, stream>>>(
      ipwb + 1536 * 768, WyT, zb, Wkv + 768 * 1024, 768, 1024, 768, 8);
  k_bfuse<<<dim3(576), dim3(256), 0, stream>>>(ipw, ipb, bx, by, bqx, bkv);
  k_qprompt<<<dim3(768), dim3(256), 0, stream>>>(ipw, ipb, prompt, qpf);

  // ---- x -> bf16; q_x = xb @ Wqx^T + bqx  (M=18432, N=768, K=1536) ----
  k_cvt<<<dim3(2048), dim3(256), 0, stream>>>(x, xb, 18432L * 1536 / 8);
  k_gemm<unsigned short><<<dim3(144 * 6), dim3(256), 0, stream>>>(
      xb, Wqx, bqx, qxb, 18432, 768, 1536, 6);

  // ---- kv = bf16(y) @ Wkv^T + bkv  (M=294912, N=1536, K=1024), 8-phase ----
  long row0 = 0;
  while (row0 < 294912) {
    long mc = 294912 - row0 < rpc ? 294912 - row0 : rpc;
    k_cvt<<<dim3(2048), dim3(256), 0, stream>>>(y + row0 * 1024, ybc, mc * 128);
    k_gemm8<unsigned short><<<dim3((int)(mc / 256) * 6), dim3(512), 0, stream>>>(
        ybc, Wkv, bkv, kvb + row0 * 1536, (int)mc, 1536, 1024, 6);
    row0 += mc;
  }

  // ---- attention -> o bf16 ----
  k_attn<<<dim3(9216), dim3(512), 0, stream>>>(kvb, qxb, qpf, ob);

  // ---- out = o @ oww^T + outb  (M=92160, N=768, K=768) -> f32, 8-phase ----
  k_gemm8<float><<<dim3(360 * 3), dim3(512), 0, stream>>>(
      ob, oww, outb, out, 92160, 768, 768, 3);
}

// Round 10
// 2141.332 us; speedup vs baseline: 3.4792x; 1.1809x over previous
//
#include <hip/hip_runtime.h>
#include <hip/hip_bf16.h>

// ---------------------------------------------------------------------------
// LocalizedPromptedAttentionLayer on MI355X (gfx950) — round 10
// B=32, N=576 patches, W=16 kv-window, d=768, P=4 prompts, H=12 heads, Dh=64
//
//   xb   = bf16(x)                                [18432, 1536]  (aliased in ob)
//   q_x  = xb @ (Wq@Wx)^T + (bq + Wq@bx)          [18432, 768] bf16   (128² GEMM)
//   qprm = prompt @ Wq^T + bq                     [4, 768] bf16
//   yb   = bf16(y)  (chunked vs ws_size)          [rows, 1024]
//   kv   = yb @ [Wk@Wy ; Wv@Wy]^T + bias          [294912, 1536] bf16 (256² 8-phase)
//   o    = softmax(q k^T / 8) v                   [92160, 768] bf16
//   out  = o @ out_w^T + out_b                    [92160, 768] f32    (256² 8-phase)
//
// Round-10 vs round 9: k_attn restructured for TLP — 1 patch per 256-thread
// block (was 2 patches / 512 thr), LDS 36.4 KB -> 4 blocks/CU (was 2).
// Q staged bf16 (expand in-dot via packed ops). Mechanism: attn is
// phase-serialization/latency-bound (stage->barrier->scores->barrier->PV);
// 4 co-resident blocks give 4 overlapping pipelines per CU.
// ---------------------------------------------------------------------------

typedef __attribute__((ext_vector_type(8))) short bf16x8;   // MFMA A/B frag
typedef __attribute__((ext_vector_type(4))) float f32x4;    // MFMA C/D frag
typedef __attribute__((ext_vector_type(2))) float f32x2;
typedef __attribute__((ext_vector_type(8))) unsigned short u16x8;

__device__ __forceinline__ float bf2f(unsigned short u) {
  union { unsigned int i; float f; } x; x.i = ((unsigned int)u) << 16; return x.f;
}
__device__ __forceinline__ unsigned short f2b(float f) {
  union { float f; unsigned int i; } x; x.f = f;
  unsigned int u = x.i;
  return (unsigned short)((u + 0x7fffu + ((u >> 16) & 1u)) >> 16);  // RNE
}
__device__ __forceinline__ unsigned int cvtpk(float lo, float hi) {
  unsigned int r;
  asm("v_cvt_pk_bf16_f32 %0, %1, %2" : "=v"(r) : "v"(lo), "v"(hi));  // RNE pack
  return r;
}
// expand packed bf16 pair (one u32) to f32x2: lo = u<<16, hi = u&0xFFFF0000
__device__ __forceinline__ f32x2 bf2x(unsigned int u) {
  union { unsigned int i; float f; } lo, hi;
  lo.i = u << 16; hi.i = u & 0xFFFF0000u;
  f32x2 r; r[0] = lo.f; r[1] = hi.f; return r;
}
__device__ __forceinline__ void pkfma(f32x2& acc, f32x2 a, f32x2 b) {
  asm("v_pk_fma_f32 %0, %1, %2, %0" : "+v"(acc) : "v"(a), "v"(b));
}

#define GLDS(gaddr, laddr) \
  __builtin_amdgcn_global_load_lds( \
      (const __attribute__((address_space(1))) unsigned int*)(gaddr), \
      (__attribute__((address_space(3))) unsigned int*)(laddr), 16, 0, 0)

// ---------------- f32 -> bf16 bulk convert (8 elems/thread-iter) ----------------
__global__ void k_cvt(const float* __restrict__ src, unsigned short* __restrict__ dst, long n8) {
  long stride = (long)gridDim.x * blockDim.x;
  for (long i = (long)blockIdx.x * blockDim.x + threadIdx.x; i < n8; i += stride) {
    float4 a = ((const float4*)src)[2 * i];
    float4 b = ((const float4*)src)[2 * i + 1];
    u16x8 t = { f2b(a.x), f2b(a.y), f2b(a.z), f2b(a.w),
                f2b(b.x), f2b(b.y), f2b(b.z), f2b(b.w) };
    ((u16x8*)dst)[i] = t;
  }
}

// ---------------- tiled transpose: src[R][C] f32 -> dst[C][R] bf16 ----------------
__global__ __launch_bounds__(256) void k_tr(const float* __restrict__ src,
                                            unsigned short* __restrict__ dst,
                                            int R, int C) {
  __shared__ float t[32][33];
  int bx = blockIdx.x * 32, by = blockIdx.y * 32;
  int lx = threadIdx.x & 31, ly = threadIdx.x >> 5;   // 32 x 8
#pragma unroll
  for (int s = 0; s < 32; s += 8)
    t[ly + s][lx] = src[(long)(by + ly + s) * C + bx + lx];
  __syncthreads();
#pragma unroll
  for (int s = 0; s < 32; s += 8)
    dst[(long)(bx + ly + s) * R + by + lx] = f2b(t[lx][ly + s]);
}

// ---------------- zero fill ----------------
__global__ void k_zf(float* __restrict__ p, int n) {
  int i = blockIdx.x * 256 + threadIdx.x;
  if (i < n) p[i] = 0.f;
}

// ---------------- fused biases ----------------
__global__ void k_bfuse(const float* __restrict__ ipw, const float* __restrict__ ipb,
                        const float* __restrict__ bx, const float* __restrict__ by,
                        float* __restrict__ bqx, float* __restrict__ bkv) {
  int o    = blockIdx.x * 4 + (threadIdx.x >> 6);   // 0..2303 (grid 576)
  int lane = threadIdx.x & 63;
  int sec  = o / 768, jj = o - sec * 768;
  const float* Arow = ipw + (long)o * 768;
  const float* vb   = (sec == 0) ? bx : by;
  float s = 0.f;
  for (int k = lane; k < 768; k += 64) s += Arow[k] * vb[k];
#pragma unroll
  for (int d = 32; d > 0; d >>= 1) s += __shfl_down(s, d);
  if (lane == 0) {
    s += ipb[o];
    if (sec == 0) bqx[jj] = s;
    else if (sec == 1) bkv[jj] = s;
    else bkv[768 + jj] = s;
  }
}

// ---------------- prompt queries ----------------
__global__ void k_qprompt(const float* __restrict__ ipw, const float* __restrict__ ipb,
                          const float* __restrict__ prompt, unsigned short* __restrict__ qpf) {
  int o    = blockIdx.x * 4 + (threadIdx.x >> 6);   // 0..3071 (grid 768)
  int lane = threadIdx.x & 63;
  int p = o / 768, j = o - p * 768;
  const float* Wqr = ipw + (long)j * 768;
  const float* pr  = prompt + (long)p * 768;
  float s = 0.f;
  for (int k = lane; k < 768; k += 64) s += Wqr[k] * pr[k];
#pragma unroll
  for (int d = 32; d > 0; d >>= 1) s += __shfl_down(s, d);
  if (lane == 0) qpf[o] = f2b(s + ipb[j]);
}

// ---------------- 128² GEMM (proven m97 structure) ----------------
template <typename OutT>
__global__ __launch_bounds__(256) void k_gemm(const unsigned short* __restrict__ A,
                                              const unsigned short* __restrict__ Bw,
                                              const float* __restrict__ bias,
                                              OutT* __restrict__ C,
                                              int M, int Nn, int K, int nbx) {
  const int tid  = threadIdx.x;
  const int lane = tid & 63, wid = tid >> 6;
  const int wm = wid >> 1, wn = wid & 1;
  const int lr = lane & 15, lk = lane >> 4;

  const int nwg = gridDim.x, orig = blockIdx.x;
  const int q8 = nwg >> 3, r8 = nwg & 7, xc = orig & 7;
  const int wg = (xc < r8 ? xc * (q8 + 1) : r8 * (q8 + 1) + (xc - r8) * q8) + (orig >> 3);
  const int bn = wg % nbx, bm = wg / nbx;
  const int m0 = bm * 128, n0 = bn * 128;

  __shared__ __attribute__((aligned(16))) unsigned short As[2][128 * 32];
  __shared__ __attribute__((aligned(16))) unsigned short Bs[2][128 * 32];

  f32x4 acc[4][4];
#pragma unroll
  for (int nt = 0; nt < 4; ++nt) {
    float bv = bias[n0 + wn * 64 + nt * 16 + lr];
    f32x4 bvv = {bv, bv, bv, bv};
#pragma unroll
    for (int mt = 0; mt < 4; ++mt) acc[mt][nt] = bvv;
  }

  const int NS = K >> 5;
  const int crow = lane >> 2, ck8 = (lane & 3) * 8;

  auto stage = [&](int buf, int ks) {
#pragma unroll
    for (int i = 0; i < 2; ++i) {
      int c = wid * 2 + i;
      int row = c * 16 + crow;
      GLDS(&A[(long)(m0 + row) * K + ks * 32 + ck8], &As[buf][c * 512]);
      GLDS(&Bw[(long)(n0 + row) * K + ks * 32 + ck8], &Bs[buf][c * 512]);
    }
  };

  stage(0, 0);
  __syncthreads();

  for (int t = 0; t < NS; ++t) {
    const int cur = t & 1, nb = cur ^ 1;
    if (t + 1 < NS) stage(nb, t + 1);
    bf16x8 af[4], bfr[4];
#pragma unroll
    for (int mt = 0; mt < 4; ++mt)
      af[mt] = *(const bf16x8*)&As[cur][(wm * 64 + mt * 16 + lr) * 32 + lk * 8];
#pragma unroll
    for (int nt = 0; nt < 4; ++nt)
      bfr[nt] = *(const bf16x8*)&Bs[cur][(wn * 64 + nt * 16 + lr) * 32 + lk * 8];
#pragma unroll
    for (int mt = 0; mt < 4; ++mt)
#pragma unroll
      for (int nt = 0; nt < 4; ++nt)
        acc[mt][nt] = __builtin_amdgcn_mfma_f32_16x16x32_bf16(af[mt], bfr[nt], acc[mt][nt], 0, 0, 0);
    __syncthreads();
  }

#pragma unroll
  for (int mt = 0; mt < 4; ++mt)
#pragma unroll
    for (int nt = 0; nt < 4; ++nt) {
      int col = n0 + wn * 64 + nt * 16 + lr;
#pragma unroll
      for (int r = 0; r < 4; ++r) {
        int row = m0 + wm * 64 + mt * 16 + lk * 4 + r;
        float v = acc[mt][nt][r];
        if constexpr (sizeof(OutT) == 4) C[(long)row * Nn + col] = v;
        else                             C[(long)row * Nn + col] = f2b(v);
      }
    }
}

// ---------------- 256² 8-phase GEMM (round-5 proven schedule) ----------------
template <typename OutT>
__global__ __launch_bounds__(512, 2) void k_gemm8(const unsigned short* __restrict__ A,
                                                  const unsigned short* __restrict__ Bw,
                                                  const float* __restrict__ bias,
                                                  OutT* __restrict__ C,
                                                  int M, int Nn, int K, int nbx) {
  const int tid  = threadIdx.x;
  const int lane = tid & 63, wid = tid >> 6;
  const int wm = wid >> 2, wn = wid & 3;          // 2 x 4 waves
  const int lr = lane & 15, lk = lane >> 4;

  const int nwg = gridDim.x, orig = blockIdx.x;
  const int q8 = nwg >> 3, r8 = nwg & 7, xc = orig & 7;
  const int wg = (xc < r8 ? xc * (q8 + 1) : r8 * (q8 + 1) + (xc - r8) * q8) + (orig >> 3);
  const int bn = wg % nbx, bm = wg / nbx;
  const long m0 = (long)bm * 256, n0 = (long)bn * 256;

  __shared__ __attribute__((aligned(16))) unsigned short As[2][2][8192];  // [buf][half][128*64]
  __shared__ __attribute__((aligned(16))) unsigned short Bs[2][2][8192];

  f32x4 acc[8][4];
#pragma unroll
  for (int nt = 0; nt < 4; ++nt) {
    float bv = bias[n0 + wn * 64 + nt * 16 + lr];
    f32x4 bvv = {bv, bv, bv, bv};
#pragma unroll
    for (int mt = 0; mt < 8; ++mt) acc[mt][nt] = bvv;
  }

  const int NT = K >> 6;            // K-tiles of 64

  auto stage = [&](int buf, int kt, int isB, int h) {
#pragma unroll
    for (int j = 0; j < 2; ++j) {
      int c   = j * 8 + wid;                         // 1KB chunk (wave-uniform)
      int row = c * 8 + (lane >> 3);                 // 0..127
      int col = ((lane & 7) * 8) ^ ((row & 7) << 3); // elems, inverse-swizzled
      const unsigned short* g = isB
          ? &Bw[(n0 + h * 128 + row) * (long)K + kt * 64 + col]
          : &A [(m0 + h * 128 + row) * (long)K + kt * 64 + col];
      unsigned short* l = isB ? &Bs[buf][h][c * 512] : &As[buf][h][c * 512];
      GLDS(g, l);
    }
  };
  auto ldsA = [&](int buf, int mt, int kk) -> bf16x8 {
    int r = mt * 16 + lr;
    int off = r * 128 + ((kk * 64 + lk * 16) ^ ((lr & 7) << 4));   // bytes
    return *(const bf16x8*)((const char*)&As[buf][wm][0] + off);
  };
  auto ldsB = [&](int buf, int nt, int kk) -> bf16x8 {
    int r = (wn & 1) * 64 + nt * 16 + lr;
    int off = r * 128 + ((kk * 64 + lk * 16) ^ ((lr & 7) << 4));
    return *(const bf16x8*)((const char*)&Bs[buf][wn >> 1][0] + off);
  };

  // ---- prologue: tile0 (all 4 halves) + tile1 A-half0 ----
  stage(0, 0, 0, 0); stage(0, 0, 0, 1); stage(0, 0, 1, 0); stage(0, 0, 1, 1);
  if (NT > 1) {
    stage(1, 1, 0, 0);
    asm volatile("s_waitcnt vmcnt(2)" ::: "memory");
  } else {
    asm volatile("s_waitcnt vmcnt(0)" ::: "memory");
  }
  __builtin_amdgcn_s_barrier();

  for (int u = 0; u < NT; ++u) {
    const int cb = u & 1;
    bf16x8 a[4][2], b0[2][2], b1[2][2];

    // ---- P1 ----
#pragma unroll
    for (int mt = 0; mt < 4; ++mt) { a[mt][0] = ldsA(cb, mt, 0); a[mt][1] = ldsA(cb, mt, 1); }
#pragma unroll
    for (int nt = 0; nt < 2; ++nt) { b0[nt][0] = ldsB(cb, nt, 0); b0[nt][1] = ldsB(cb, nt, 1); }
    if (u + 1 < NT) stage(cb ^ 1, u + 1, 0, 1);
    __builtin_amdgcn_s_barrier();
    asm volatile("s_waitcnt lgkmcnt(0)" ::: "memory");
    __builtin_amdgcn_s_setprio(1);
#pragma unroll
    for (int mt = 0; mt < 4; ++mt)
#pragma unroll
      for (int nt = 0; nt < 2; ++nt)
#pragma unroll
        for (int kk = 0; kk < 2; ++kk)
          acc[mt][nt] = __builtin_amdgcn_mfma_f32_16x16x32_bf16(a[mt][kk], b0[nt][kk], acc[mt][nt], 0, 0, 0);
    __builtin_amdgcn_s_setprio(0);
    __builtin_amdgcn_s_barrier();

    // ---- P2 ----
#pragma unroll
    for (int nt = 0; nt < 2; ++nt) { b1[nt][0] = ldsB(cb, 2 + nt, 0); b1[nt][1] = ldsB(cb, 2 + nt, 1); }
    if (u + 1 < NT) stage(cb ^ 1, u + 1, 1, 0);
    __builtin_amdgcn_s_barrier();
    asm volatile("s_waitcnt lgkmcnt(0)" ::: "memory");
    __builtin_amdgcn_s_setprio(1);
#pragma unroll
    for (int mt = 0; mt < 4; ++mt)
#pragma unroll
      for (int nt = 0; nt < 2; ++nt)
#pragma unroll
        for (int kk = 0; kk < 2; ++kk)
          acc[mt][2 + nt] = __builtin_amdgcn_mfma_f32_16x16x32_bf16(a[mt][kk], b1[nt][kk], acc[mt][2 + nt], 0, 0, 0);
    __builtin_amdgcn_s_setprio(0);
    __builtin_amdgcn_s_barrier();

    // ---- P3 ----
#pragma unroll
    for (int mt = 0; mt < 4; ++mt) { a[mt][0] = ldsA(cb, 4 + mt, 0); a[mt][1] = ldsA(cb, 4 + mt, 1); }
    if (u + 1 < NT) stage(cb ^ 1, u + 1, 1, 1);
    __builtin_amdgcn_s_barrier();
    asm volatile("s_waitcnt lgkmcnt(0)" ::: "memory");
    __builtin_amdgcn_s_setprio(1);
#pragma unroll
    for (int mt = 0; mt < 4; ++mt)
#pragma unroll
      for (int nt = 0; nt < 2; ++nt)
#pragma unroll
        for (int kk = 0; kk < 2; ++kk)
          acc[4 + mt][2 + nt] = __builtin_amdgcn_mfma_f32_16x16x32_bf16(a[mt][kk], b1[nt][kk], acc[4 + mt][2 + nt], 0, 0, 0);
    __builtin_amdgcn_s_setprio(0);
    __builtin_amdgcn_s_barrier();

    // ---- P4 ----
    if (u + 2 < NT) stage(cb, u + 2, 0, 0);
    __builtin_amdgcn_s_barrier();
    __builtin_amdgcn_s_setprio(1);
#pragma unroll
    for (int mt = 0; mt < 4; ++mt)
#pragma unroll
      for (int nt = 0; nt < 2; ++nt)
#pragma unroll
        for (int kk = 0; kk < 2; ++kk)
          acc[4 + mt][nt] = __builtin_amdgcn_mfma_f32_16x16x32_bf16(a[mt][kk], b0[nt][kk], acc[4 + mt][nt], 0, 0, 0);
    __builtin_amdgcn_s_setprio(0);
    // counted drain BEFORE the closing barrier (cross-wave publish, r5 rule)
    if (u + 2 < NT)       asm volatile("s_waitcnt vmcnt(2)" ::: "memory");
    else if (u + 1 < NT)  asm volatile("s_waitcnt vmcnt(0)" ::: "memory");
    __builtin_amdgcn_s_barrier();
  }

  // ---- epilogue ----
#pragma unroll
  for (int mt = 0; mt < 8; ++mt)
#pragma unroll
    for (int nt = 0; nt < 4; ++nt) {
      long col = n0 + wn * 64 + nt * 16 + lr;
#pragma unroll
      for (int r = 0; r < 4; ++r) {
        long row = m0 + wm * 128 + mt * 16 + lk * 4 + r;
        float v = acc[mt][nt][r];
        if constexpr (sizeof(OutT) == 4) C[row * Nn + col] = v;
        else                             C[row * Nn + col] = f2b(v);
      }
    }
}

// ---------------- attention: 1 patch / 256 threads / 4 blocks per CU ----------------
// LDS 36.4 KB: Ks[16][776] bf16 (aligned b128, 2-way banks), Qs[5][768] bf16,
// Ss[60][16] f32. Scores: 16-lane w-groups, packed-f32 dots (bf16-pair expand),
// shfl softmax. PV: 8 outputs/lane, coalesced v from global, cvt_pk output.
__global__ __launch_bounds__(256) void k_attn(const unsigned short* __restrict__ kv,
                                              const unsigned short* __restrict__ qx,
                                              const unsigned short* __restrict__ qp,
                                              unsigned short* __restrict__ o) {
  __shared__ __attribute__((aligned(16))) unsigned short Ks[16 * 776];
  __shared__ __attribute__((aligned(16))) unsigned short Qs[5 * 768];
  __shared__ float Ss[60 * 16];
  const int tid = threadIdx.x;
  const long pp = (long)blockIdx.x;          // patch id 0..18431

  // stage K (k-half of this patch's 16 kv rows): 1536 chunks / 256 thr
  for (int i = tid; i < 16 * 96; i += 256) {
    int r = i / 96, c8 = i - r * 96;
    *(u16x8*)&Ks[r * 776 + c8 * 8] =
        *(const u16x8*)&kv[(pp * 16 + r) * 1536 + c8 * 8];
  }
  // stage Q bf16: row0 = qx[pp], rows 1-4 = prompts
  for (int i = tid; i < 5 * 96; i += 256) {
    int r = i / 96, c8 = i - r * 96;
    const unsigned short* src = (r == 0) ? &qx[pp * 768 + c8 * 8]
                                         : &qp[(long)(r - 1) * 768 + c8 * 8];
    *(u16x8*)&Qs[r * 768 + c8 * 8] = *(const u16x8*)src;
  }
  __syncthreads();

  // scores + softmax: 5q x 12h x 16w = 960 items (16-lane w-groups)
  for (int idx = tid; idx < 960; idx += 256) {
    int w = idx & 15, rest = idx >> 4;       // rest = q5*12 + h
    int h = rest % 12, q5 = rest / 12;
    const unsigned int* kr = (const unsigned int*)&Ks[w * 776 + h * 64];
    const unsigned int* qr = (const unsigned int*)&Qs[q5 * 768 + h * 64];
    f32x2 a2 = {0.f, 0.f};
#pragma unroll
    for (int j = 0; j < 8; ++j) {
      uint4 kw = *(const uint4*)(kr + j * 4);
      uint4 qw = *(const uint4*)(qr + j * 4);
      pkfma(a2, bf2x(kw.x), bf2x(qw.x));
      pkfma(a2, bf2x(kw.y), bf2x(qw.y));
      pkfma(a2, bf2x(kw.z), bf2x(qw.z));
      pkfma(a2, bf2x(kw.w), bf2x(qw.w));
    }
    float s = (a2[0] + a2[1]) * 0.125f;
    float m = s;
#pragma unroll
    for (int d = 1; d < 16; d <<= 1) m = fmaxf(m, __shfl_xor(m, d));
    float e = __expf(s - m);
    float sum = e;
#pragma unroll
    for (int d = 1; d < 16; d <<= 1) sum += __shfl_xor(sum, d);
    Ss[rest * 16 + w] = e / sum;
  }
  __syncthreads();

  // PV: 5q x 96 d8-chunks = 480 items; 8 outputs/lane, v 16B/lane coalesced
  for (int idx = tid; idx < 480; idx += 256) {
    int d8 = idx % 96, q5 = idx / 96;
    int h = d8 >> 3;
    const float* arow = &Ss[(q5 * 12 + h) * 16];
    const unsigned short* vbase = &kv[pp * 16 * 1536 + 768 + d8 * 8];
    f32x2 a0 = {0.f, 0.f}, a1 = {0.f, 0.f}, a2v = {0.f, 0.f}, a3 = {0.f, 0.f};
#pragma unroll
    for (int w = 0; w < 16; ++w) {
      uint4 vv = *(const uint4*)&vbase[(long)w * 1536];
      float aw = arow[w];
      f32x2 aw2 = {aw, aw};
      pkfma(a0,  bf2x(vv.x), aw2);
      pkfma(a1,  bf2x(vv.y), aw2);
      pkfma(a2v, bf2x(vv.z), aw2);
      pkfma(a3,  bf2x(vv.w), aw2);
    }
    uint4 pk;
    pk.x = cvtpk(a0[0],  a0[1]);
    pk.y = cvtpk(a1[0],  a1[1]);
    pk.z = cvtpk(a2v[0], a2v[1]);
    pk.w = cvtpk(a3[0],  a3[1]);
    *(uint4*)&o[(pp * 5 + q5) * 768 + d8 * 8] = pk;
  }
}

// ---------------------------------------------------------------------------
extern "C" void kernel_launch(void* const* d_in, const int* in_sizes, int n_in,
                              void* d_out, int out_size, void* d_ws, size_t ws_size,
                              hipStream_t stream) {
  const float* x      = (const float*)d_in[0];   // [32,576,1536]
  const float* y      = (const float*)d_in[1];   // [32,9216,1024]
  const float* Wx     = (const float*)d_in[2];   // [768,1536]
  const float* bx     = (const float*)d_in[3];   // [768]
  const float* Wy     = (const float*)d_in[4];   // [768,1024]
  const float* by     = (const float*)d_in[5];   // [768]
  const float* prompt = (const float*)d_in[6];   // [1,4,768]
  const float* ipw    = (const float*)d_in[7];   // [2304,768]
  const float* ipb    = (const float*)d_in[8];   // [2304]
  const float* outw   = (const float*)d_in[9];   // [768,768]
  const float* outb   = (const float*)d_in[10];  // [768]
  float* out = (float*)d_out;

  char* ws = (char*)d_ws;
  size_t off = 0;
  auto alloc = [&](size_t bytes) -> void* {
    void* p = ws + off; off += (bytes + 255) & ~(size_t)255; return p;
  };
  unsigned short* kvb  = (unsigned short*)alloc(294912UL * 1536 * 2);  // 906 MB
  unsigned short* qxb  = (unsigned short*)alloc(18432UL * 768 * 2);    // 28 MB
  unsigned short* ob   = (unsigned short*)alloc(92160UL * 768 * 2);    // 142 MB
  unsigned short* Wqx  = (unsigned short*)alloc(768UL * 1536 * 2);
  unsigned short* Wkv  = (unsigned short*)alloc(1536UL * 1024 * 2);
  unsigned short* oww  = (unsigned short*)alloc(768UL * 768 * 2);
  unsigned short* qpf  = (unsigned short*)alloc(4UL * 768 * 2);
  float*          bqx  = (float*)alloc(768 * 4);
  float*          bkv  = (float*)alloc(1536 * 4);
  unsigned short* ipwb = (unsigned short*)alloc(2304UL * 768 * 2);     // bf16 in_proj_w
  unsigned short* WxT  = (unsigned short*)alloc(1536UL * 768 * 2);     // Wx^T bf16
  unsigned short* WyT  = (unsigned short*)alloc(1024UL * 768 * 2);     // Wy^T bf16
  float*          zb   = (float*)alloc(1536 * 4);                      // zero bias
  unsigned short* xb   = ob;  // alias (dead before k_attn writes ob)
  unsigned short* ybc  = (unsigned short*)(ws + off);
  long rpc = (long)((ws_size - off) / (1024 * 2)) & ~255L;  // rows/chunk, mult of 256
  if (rpc > 294912) rpc = 294912;
  if (rpc < 256) rpc = 256;

  // ---- weight prep ----
  k_cvt<<<dim3(288), dim3(256), 0, stream>>>(outw, oww, 768L * 768 / 8);
  k_cvt<<<dim3(864), dim3(256), 0, stream>>>(ipw, ipwb, 2304L * 768 / 8);
  k_tr<<<dim3(48, 24), dim3(256), 0, stream>>>(Wx, WxT, 768, 1536);
  k_tr<<<dim3(32, 24), dim3(256), 0, stream>>>(Wy, WyT, 768, 1024);
  k_zf<<<dim3(6), dim3(256), 0, stream>>>(zb, 1536);
  // fused weights via MFMA GEMM: Wqx = Wq @ Wx  (M=768, N=1536, K=768)
  k_gemm<unsigned short><<<dim3(6 * 12), dim3(256), 0, stream>>>(
      ipwb, WxT, zb, Wqx, 768, 1536, 768, 12);
  // Wk@Wy, Wv@Wy  (M=768, N=1024, K=768)
  k_gemm<unsigned short><<<dim3(6 * 8), dim3(256), 0, stream>>>(
      ipwb + 768 * 768, WyT, zb, Wkv, 768, 1024, 768, 8);
  k_gemm<unsigned short><<<dim3(6 * 8), dim3(256), 0, stream>>>(
      ipwb + 1536 * 768, WyT, zb, Wkv + 768 * 1024, 768, 1024, 768, 8);
  k_bfuse<<<dim3(576), dim3(256), 0, stream>>>(ipw, ipb, bx, by, bqx, bkv);
  k_qprompt<<<dim3(768), dim3(256), 0, stream>>>(ipw, ipb, prompt, qpf);

  // ---- x -> bf16; q_x = xb @ Wqx^T + bqx  (M=18432, N=768, K=1536) ----
  k_cvt<<<dim3(2048), dim3(256), 0, stream>>>(x, xb, 18432L * 1536 / 8);
  k_gemm<unsigned short><<<dim3(144 * 6), dim3(256), 0, stream>>>(
      xb, Wqx, bqx, qxb, 18432, 768, 1536, 6);

  // ---- kv = bf16(y) @ Wkv^T + bkv  (M=294912, N=1536, K=1024), 8-phase ----
  long row0 = 0;
  while (row0 < 294912) {
    long mc = 294912 - row0 < rpc ? 294912 - row0 : rpc;
    k_cvt<<<dim3(2048), dim3(256), 0, stream>>>(y + row0 * 1024, ybc, mc * 128);
    k_gemm8<unsigned short><<<dim3((int)(mc / 256) * 6), dim3(512), 0, stream>>>(
        ybc, Wkv, bkv, kvb + row0 * 1536, (int)mc, 1536, 1024, 6);
    row0 += mc;
  }

  // ---- attention -> o bf16 (1 patch per block) ----
  k_attn<<<dim3(18432), dim3(256), 0, stream>>>(kvb, qxb, qpf, ob);

  // ---- out = o @ oww^T + outb  (M=92160, N=768, K=768) -> f32, 8-phase ----
  k_gemm8<float><<<dim3(360 * 3), dim3(512), 0, stream>>>(
      ob, oww, outb, out, 92160, 768, 768, 3);
}

// Round 11
// 2100.697 us; speedup vs baseline: 3.5465x; 1.0193x over previous
//
#include <hip/hip_runtime.h>
#include <hip/hip_bf16.h>

// ---------------------------------------------------------------------------
// LocalizedPromptedAttentionLayer on MI355X (gfx950) — round 11
// B=32, N=576 patches, W=16 kv-window, d=768, P=4 prompts, H=12 heads, Dh=64
//
//   xb   = bf16(x)                                [18432, 1536]  (aliased in ob)
//   q_x  = xb @ (Wq@Wx)^T + (bq + Wq@bx)          [18432, 768] bf16   (128² GEMM)
//   qprm = prompt @ Wq^T + bq                     [4, 768] bf16
//   yb   = bf16(y)  (chunked vs ws_size)          [rows, 1024]
//   kv   = yb @ [Wk@Wy ; Wv@Wy]^T + bias          bf16, ATTN-OPTIMIZED LAYOUT:
//            K' = kv[pp*24576 + h*1024 + w*64 + d]      ([patch][head][w][64])
//            V  = kv[pp*24576 + 12288 + w*768 + d]      ([patch][w][768])
//   o    = softmax(q k^T / 8) v                   [92160, 768] bf16
//   out  = o @ out_w^T + out_b                    [92160, 768] f32    (256² 8-phase)
//
// Round-11 vs round 10: kv K-half written in [patch][h][w][64] order so attn
// lanes (h,w) read K directly from global fully coalesced — K LDS tile
// eliminated (36.4 -> 11.3 KB), occupancy 4 -> ~6-8 blocks/CU, stage-K phase
// gone. GEMM epilogue addressing-only change (same 16-lane x 2B contiguity).
// ---------------------------------------------------------------------------

typedef __attribute__((ext_vector_type(8))) short bf16x8;   // MFMA A/B frag
typedef __attribute__((ext_vector_type(4))) float f32x4;    // MFMA C/D frag
typedef __attribute__((ext_vector_type(2))) float f32x2;
typedef __attribute__((ext_vector_type(8))) unsigned short u16x8;

__device__ __forceinline__ float bf2f(unsigned short u) {
  union { unsigned int i; float f; } x; x.i = ((unsigned int)u) << 16; return x.f;
}
__device__ __forceinline__ unsigned short f2b(float f) {
  union { float f; unsigned int i; } x; x.f = f;
  unsigned int u = x.i;
  return (unsigned short)((u + 0x7fffu + ((u >> 16) & 1u)) >> 16);  // RNE
}
__device__ __forceinline__ unsigned int cvtpk(float lo, float hi) {
  unsigned int r;
  asm("v_cvt_pk_bf16_f32 %0, %1, %2" : "=v"(r) : "v"(lo), "v"(hi));  // RNE pack
  return r;
}
// expand packed bf16 pair (one u32) to f32x2: lo = u<<16, hi = u&0xFFFF0000
__device__ __forceinline__ f32x2 bf2x(unsigned int u) {
  union { unsigned int i; float f; } lo, hi;
  lo.i = u << 16; hi.i = u & 0xFFFF0000u;
  f32x2 r; r[0] = lo.f; r[1] = hi.f; return r;
}
__device__ __forceinline__ void pkfma(f32x2& acc, f32x2 a, f32x2 b) {
  asm("v_pk_fma_f32 %0, %1, %2, %0" : "+v"(acc) : "v"(a), "v"(b));
}

#define GLDS(gaddr, laddr) \
  __builtin_amdgcn_global_load_lds( \
      (const __attribute__((address_space(1))) unsigned int*)(gaddr), \
      (__attribute__((address_space(3))) unsigned int*)(laddr), 16, 0, 0)

// ---------------- f32 -> bf16 bulk convert (8 elems/thread-iter) ----------------
__global__ void k_cvt(const float* __restrict__ src, unsigned short* __restrict__ dst, long n8) {
  long stride = (long)gridDim.x * blockDim.x;
  for (long i = (long)blockIdx.x * blockDim.x + threadIdx.x; i < n8; i += stride) {
    float4 a = ((const float4*)src)[2 * i];
    float4 b = ((const float4*)src)[2 * i + 1];
    u16x8 t = { f2b(a.x), f2b(a.y), f2b(a.z), f2b(a.w),
                f2b(b.x), f2b(b.y), f2b(b.z), f2b(b.w) };
    ((u16x8*)dst)[i] = t;
  }
}

// ---------------- tiled transpose: src[R][C] f32 -> dst[C][R] bf16 ----------------
__global__ __launch_bounds__(256) void k_tr(const float* __restrict__ src,
                                            unsigned short* __restrict__ dst,
                                            int R, int C) {
  __shared__ float t[32][33];
  int bx = blockIdx.x * 32, by = blockIdx.y * 32;
  int lx = threadIdx.x & 31, ly = threadIdx.x >> 5;   // 32 x 8
#pragma unroll
  for (int s = 0; s < 32; s += 8)
    t[ly + s][lx] = src[(long)(by + ly + s) * C + bx + lx];
  __syncthreads();
#pragma unroll
  for (int s = 0; s < 32; s += 8)
    dst[(long)(bx + ly + s) * R + by + lx] = f2b(t[lx][ly + s]);
}

// ---------------- zero fill ----------------
__global__ void k_zf(float* __restrict__ p, int n) {
  int i = blockIdx.x * 256 + threadIdx.x;
  if (i < n) p[i] = 0.f;
}

// ---------------- fused biases ----------------
__global__ void k_bfuse(const float* __restrict__ ipw, const float* __restrict__ ipb,
                        const float* __restrict__ bx, const float* __restrict__ by,
                        float* __restrict__ bqx, float* __restrict__ bkv) {
  int o    = blockIdx.x * 4 + (threadIdx.x >> 6);   // 0..2303 (grid 576)
  int lane = threadIdx.x & 63;
  int sec  = o / 768, jj = o - sec * 768;
  const float* Arow = ipw + (long)o * 768;
  const float* vb   = (sec == 0) ? bx : by;
  float s = 0.f;
  for (int k = lane; k < 768; k += 64) s += Arow[k] * vb[k];
#pragma unroll
  for (int d = 32; d > 0; d >>= 1) s += __shfl_down(s, d);
  if (lane == 0) {
    s += ipb[o];
    if (sec == 0) bqx[jj] = s;
    else if (sec == 1) bkv[jj] = s;
    else bkv[768 + jj] = s;
  }
}

// ---------------- prompt queries ----------------
__global__ void k_qprompt(const float* __restrict__ ipw, const float* __restrict__ ipb,
                          const float* __restrict__ prompt, unsigned short* __restrict__ qpf) {
  int o    = blockIdx.x * 4 + (threadIdx.x >> 6);   // 0..3071 (grid 768)
  int lane = threadIdx.x & 63;
  int p = o / 768, j = o - p * 768;
  const float* Wqr = ipw + (long)j * 768;
  const float* pr  = prompt + (long)p * 768;
  float s = 0.f;
  for (int k = lane; k < 768; k += 64) s += Wqr[k] * pr[k];
#pragma unroll
  for (int d = 32; d > 0; d >>= 1) s += __shfl_down(s, d);
  if (lane == 0) qpf[o] = f2b(s + ipb[j]);
}

// ---------------- 128² GEMM (proven m97 structure) ----------------
template <typename OutT>
__global__ __launch_bounds__(256) void k_gemm(const unsigned short* __restrict__ A,
                                              const unsigned short* __restrict__ Bw,
                                              const float* __restrict__ bias,
                                              OutT* __restrict__ C,
                                              int M, int Nn, int K, int nbx) {
  const int tid  = threadIdx.x;
  const int lane = tid & 63, wid = tid >> 6;
  const int wm = wid >> 1, wn = wid & 1;
  const int lr = lane & 15, lk = lane >> 4;

  const int nwg = gridDim.x, orig = blockIdx.x;
  const int q8 = nwg >> 3, r8 = nwg & 7, xc = orig & 7;
  const int wg = (xc < r8 ? xc * (q8 + 1) : r8 * (q8 + 1) + (xc - r8) * q8) + (orig >> 3);
  const int bn = wg % nbx, bm = wg / nbx;
  const int m0 = bm * 128, n0 = bn * 128;

  __shared__ __attribute__((aligned(16))) unsigned short As[2][128 * 32];
  __shared__ __attribute__((aligned(16))) unsigned short Bs[2][128 * 32];

  f32x4 acc[4][4];
#pragma unroll
  for (int nt = 0; nt < 4; ++nt) {
    float bv = bias[n0 + wn * 64 + nt * 16 + lr];
    f32x4 bvv = {bv, bv, bv, bv};
#pragma unroll
    for (int mt = 0; mt < 4; ++mt) acc[mt][nt] = bvv;
  }

  const int NS = K >> 5;
  const int crow = lane >> 2, ck8 = (lane & 3) * 8;

  auto stage = [&](int buf, int ks) {
#pragma unroll
    for (int i = 0; i < 2; ++i) {
      int c = wid * 2 + i;
      int row = c * 16 + crow;
      GLDS(&A[(long)(m0 + row) * K + ks * 32 + ck8], &As[buf][c * 512]);
      GLDS(&Bw[(long)(n0 + row) * K + ks * 32 + ck8], &Bs[buf][c * 512]);
    }
  };

  stage(0, 0);
  __syncthreads();

  for (int t = 0; t < NS; ++t) {
    const int cur = t & 1, nb = cur ^ 1;
    if (t + 1 < NS) stage(nb, t + 1);
    bf16x8 af[4], bfr[4];
#pragma unroll
    for (int mt = 0; mt < 4; ++mt)
      af[mt] = *(const bf16x8*)&As[cur][(wm * 64 + mt * 16 + lr) * 32 + lk * 8];
#pragma unroll
    for (int nt = 0; nt < 4; ++nt)
      bfr[nt] = *(const bf16x8*)&Bs[cur][(wn * 64 + nt * 16 + lr) * 32 + lk * 8];
#pragma unroll
    for (int mt = 0; mt < 4; ++mt)
#pragma unroll
      for (int nt = 0; nt < 4; ++nt)
        acc[mt][nt] = __builtin_amdgcn_mfma_f32_16x16x32_bf16(af[mt], bfr[nt], acc[mt][nt], 0, 0, 0);
    __syncthreads();
  }

#pragma unroll
  for (int mt = 0; mt < 4; ++mt)
#pragma unroll
    for (int nt = 0; nt < 4; ++nt) {
      int col = n0 + wn * 64 + nt * 16 + lr;
#pragma unroll
      for (int r = 0; r < 4; ++r) {
        int row = m0 + wm * 64 + mt * 16 + lk * 4 + r;
        float v = acc[mt][nt][r];
        if constexpr (sizeof(OutT) == 4) C[(long)row * Nn + col] = v;
        else                             C[(long)row * Nn + col] = f2b(v);
      }
    }
}

// ---------------- 256² 8-phase GEMM (round-5 proven schedule) ----------------
// KVL=true: C written in the attention-optimized kv layout (see header).
template <bool KVL, typename OutT>
__global__ __launch_bounds__(512, 2) void k_gemm8(const unsigned short* __restrict__ A,
                                                  const unsigned short* __restrict__ Bw,
                                                  const float* __restrict__ bias,
                                                  OutT* __restrict__ C,
                                                  int M, int Nn, int K, int nbx) {
  const int tid  = threadIdx.x;
  const int lane = tid & 63, wid = tid >> 6;
  const int wm = wid >> 2, wn = wid & 3;          // 2 x 4 waves
  const int lr = lane & 15, lk = lane >> 4;

  const int nwg = gridDim.x, orig = blockIdx.x;
  const int q8 = nwg >> 3, r8 = nwg & 7, xc = orig & 7;
  const int wg = (xc < r8 ? xc * (q8 + 1) : r8 * (q8 + 1) + (xc - r8) * q8) + (orig >> 3);
  const int bn = wg % nbx, bm = wg / nbx;
  const long m0 = (long)bm * 256, n0 = (long)bn * 256;

  __shared__ __attribute__((aligned(16))) unsigned short As[2][2][8192];  // [buf][half][128*64]
  __shared__ __attribute__((aligned(16))) unsigned short Bs[2][2][8192];

  f32x4 acc[8][4];
#pragma unroll
  for (int nt = 0; nt < 4; ++nt) {
    float bv = bias[n0 + wn * 64 + nt * 16 + lr];
    f32x4 bvv = {bv, bv, bv, bv};
#pragma unroll
    for (int mt = 0; mt < 8; ++mt) acc[mt][nt] = bvv;
  }

  const int NT = K >> 6;            // K-tiles of 64

  auto stage = [&](int buf, int kt, int isB, int h) {
#pragma unroll
    for (int j = 0; j < 2; ++j) {
      int c   = j * 8 + wid;                         // 1KB chunk (wave-uniform)
      int row = c * 8 + (lane >> 3);                 // 0..127
      int col = ((lane & 7) * 8) ^ ((row & 7) << 3); // elems, inverse-swizzled
      const unsigned short* g = isB
          ? &Bw[(n0 + h * 128 + row) * (long)K + kt * 64 + col]
          : &A [(m0 + h * 128 + row) * (long)K + kt * 64 + col];
      unsigned short* l = isB ? &Bs[buf][h][c * 512] : &As[buf][h][c * 512];
      GLDS(g, l);
    }
  };
  auto ldsA = [&](int buf, int mt, int kk) -> bf16x8 {
    int r = mt * 16 + lr;
    int off = r * 128 + ((kk * 64 + lk * 16) ^ ((lr & 7) << 4));   // bytes
    return *(const bf16x8*)((const char*)&As[buf][wm][0] + off);
  };
  auto ldsB = [&](int buf, int nt, int kk) -> bf16x8 {
    int r = (wn & 1) * 64 + nt * 16 + lr;
    int off = r * 128 + ((kk * 64 + lk * 16) ^ ((lr & 7) << 4));
    return *(const bf16x8*)((const char*)&Bs[buf][wn >> 1][0] + off);
  };

  // ---- prologue: tile0 (all 4 halves) + tile1 A-half0 ----
  stage(0, 0, 0, 0); stage(0, 0, 0, 1); stage(0, 0, 1, 0); stage(0, 0, 1, 1);
  if (NT > 1) {
    stage(1, 1, 0, 0);
    asm volatile("s_waitcnt vmcnt(2)" ::: "memory");
  } else {
    asm volatile("s_waitcnt vmcnt(0)" ::: "memory");
  }
  __builtin_amdgcn_s_barrier();

  for (int u = 0; u < NT; ++u) {
    const int cb = u & 1;
    bf16x8 a[4][2], b0[2][2], b1[2][2];

    // ---- P1 ----
#pragma unroll
    for (int mt = 0; mt < 4; ++mt) { a[mt][0] = ldsA(cb, mt, 0); a[mt][1] = ldsA(cb, mt, 1); }
#pragma unroll
    for (int nt = 0; nt < 2; ++nt) { b0[nt][0] = ldsB(cb, nt, 0); b0[nt][1] = ldsB(cb, nt, 1); }
    if (u + 1 < NT) stage(cb ^ 1, u + 1, 0, 1);
    __builtin_amdgcn_s_barrier();
    asm volatile("s_waitcnt lgkmcnt(0)" ::: "memory");
    __builtin_amdgcn_s_setprio(1);
#pragma unroll
    for (int mt = 0; mt < 4; ++mt)
#pragma unroll
      for (int nt = 0; nt < 2; ++nt)
#pragma unroll
        for (int kk = 0; kk < 2; ++kk)
          acc[mt][nt] = __builtin_amdgcn_mfma_f32_16x16x32_bf16(a[mt][kk], b0[nt][kk], acc[mt][nt], 0, 0, 0);
    __builtin_amdgcn_s_setprio(0);
    __builtin_amdgcn_s_barrier();

    // ---- P2 ----
#pragma unroll
    for (int nt = 0; nt < 2; ++nt) { b1[nt][0] = ldsB(cb, 2 + nt, 0); b1[nt][1] = ldsB(cb, 2 + nt, 1); }
    if (u + 1 < NT) stage(cb ^ 1, u + 1, 1, 0);
    __builtin_amdgcn_s_barrier();
    asm volatile("s_waitcnt lgkmcnt(0)" ::: "memory");
    __builtin_amdgcn_s_setprio(1);
#pragma unroll
    for (int mt = 0; mt < 4; ++mt)
#pragma unroll
      for (int nt = 0; nt < 2; ++nt)
#pragma unroll
        for (int kk = 0; kk < 2; ++kk)
          acc[mt][2 + nt] = __builtin_amdgcn_mfma_f32_16x16x32_bf16(a[mt][kk], b1[nt][kk], acc[mt][2 + nt], 0, 0, 0);
    __builtin_amdgcn_s_setprio(0);
    __builtin_amdgcn_s_barrier();

    // ---- P3 ----
#pragma unroll
    for (int mt = 0; mt < 4; ++mt) { a[mt][0] = ldsA(cb, 4 + mt, 0); a[mt][1] = ldsA(cb, 4 + mt, 1); }
    if (u + 1 < NT) stage(cb ^ 1, u + 1, 1, 1);
    __builtin_amdgcn_s_barrier();
    asm volatile("s_waitcnt lgkmcnt(0)" ::: "memory");
    __builtin_amdgcn_s_setprio(1);
#pragma unroll
    for (int mt = 0; mt < 4; ++mt)
#pragma unroll
      for (int nt = 0; nt < 2; ++nt)
#pragma unroll
        for (int kk = 0; kk < 2; ++kk)
          acc[4 + mt][2 + nt] = __builtin_amdgcn_mfma_f32_16x16x32_bf16(a[mt][kk], b1[nt][kk], acc[4 + mt][2 + nt], 0, 0, 0);
    __builtin_amdgcn_s_setprio(0);
    __builtin_amdgcn_s_barrier();

    // ---- P4 ----
    if (u + 2 < NT) stage(cb, u + 2, 0, 0);
    __builtin_amdgcn_s_barrier();
    __builtin_amdgcn_s_setprio(1);
#pragma unroll
    for (int mt = 0; mt < 4; ++mt)
#pragma unroll
      for (int nt = 0; nt < 2; ++nt)
#pragma unroll
        for (int kk = 0; kk < 2; ++kk)
          acc[4 + mt][nt] = __builtin_amdgcn_mfma_f32_16x16x32_bf16(a[mt][kk], b0[nt][kk], acc[4 + mt][nt], 0, 0, 0);
    __builtin_amdgcn_s_setprio(0);
    // counted drain BEFORE the closing barrier (cross-wave publish, r5 rule)
    if (u + 2 < NT)       asm volatile("s_waitcnt vmcnt(2)" ::: "memory");
    else if (u + 1 < NT)  asm volatile("s_waitcnt vmcnt(0)" ::: "memory");
    __builtin_amdgcn_s_barrier();
  }

  // ---- epilogue ----
#pragma unroll
  for (int mt = 0; mt < 8; ++mt)
#pragma unroll
    for (int nt = 0; nt < 4; ++nt) {
      long col = n0 + wn * 64 + nt * 16 + lr;
#pragma unroll
      for (int r = 0; r < 4; ++r) {
        long row = m0 + wm * 128 + mt * 16 + lk * 4 + r;
        float v = acc[mt][nt][r];
        if constexpr (KVL) {
          // attention layout: K' [pp][h][w][64] ; V [pp][w][768]
          long pp = row >> 4; int w = (int)(row & 15);
          long addr;
          if (col < 768) addr = pp * 24576 + (col >> 6) * 1024 + w * 64 + (col & 63);
          else           addr = pp * 24576 + 12288 + (long)w * 768 + (col - 768);
          C[addr] = f2b(v);
        } else if constexpr (sizeof(OutT) == 4) {
          C[row * Nn + col] = v;
        } else {
          C[row * Nn + col] = f2b(v);
        }
      }
    }
}

// ---------------- attention: LDS-light, coalesced K from global ----------------
// 1 patch / 256 threads. LDS 11.3 KB -> ~6-8 blocks/CU (VGPR-limited).
// Scores: lane (h,w) reads its K' 128B segment coalesced from global,
// loops q5 with Q from LDS (broadcast), shfl softmax in 16-lane w-groups.
// PV: as round 10 (96-lane contiguous per-w V reads), V stride now 768.
__global__ __launch_bounds__(256, 6) void k_attn(const unsigned short* __restrict__ kv,
                                                 const unsigned short* __restrict__ qx,
                                                 const unsigned short* __restrict__ qp,
                                                 unsigned short* __restrict__ o) {
  __shared__ __attribute__((aligned(16))) unsigned short Qs[5 * 768];
  __shared__ float Ss[60 * 16];
  const int tid = threadIdx.x;
  const long pp = (long)blockIdx.x;          // patch id 0..18431

  // stage Q bf16: row0 = qx[pp], rows 1-4 = prompts
  for (int i = tid; i < 5 * 96; i += 256) {
    int r = i / 96, c8 = i - r * 96;
    const unsigned short* src = (r == 0) ? &qx[pp * 768 + c8 * 8]
                                         : &qp[(long)(r - 1) * 768 + c8 * 8];
    *(u16x8*)&Qs[r * 768 + c8 * 8] = *(const u16x8*)src;
  }
  __syncthreads();

  // scores: lane = h*16 + w (192 active); K' read 128B/lane coalesced
  if (tid < 192) {
    const int h = tid >> 4, w = tid & 15;
    const uint4* kr = (const uint4*)&kv[pp * 24576 + h * 1024 + w * 64];
    f32x2 s2[5];
#pragma unroll
    for (int q5 = 0; q5 < 5; ++q5) { s2[q5][0] = 0.f; s2[q5][1] = 0.f; }
#pragma unroll
    for (int half = 0; half < 2; ++half) {
      uint4 kk0 = kr[half * 4 + 0], kk1 = kr[half * 4 + 1],
            kk2 = kr[half * 4 + 2], kk3 = kr[half * 4 + 3];
#pragma unroll
      for (int q5 = 0; q5 < 5; ++q5) {
        const uint4* qr = (const uint4*)&Qs[q5 * 768 + h * 64 + half * 32];
#pragma unroll
        for (int j = 0; j < 4; ++j) {
          uint4 kkj = (j == 0) ? kk0 : (j == 1) ? kk1 : (j == 2) ? kk2 : kk3;
          uint4 qw = qr[j];
          pkfma(s2[q5], bf2x(kkj.x), bf2x(qw.x));
          pkfma(s2[q5], bf2x(kkj.y), bf2x(qw.y));
          pkfma(s2[q5], bf2x(kkj.z), bf2x(qw.z));
          pkfma(s2[q5], bf2x(kkj.w), bf2x(qw.w));
        }
      }
    }
#pragma unroll
    for (int q5 = 0; q5 < 5; ++q5) {
      float s = (s2[q5][0] + s2[q5][1]) * 0.125f;
      float m = s;
#pragma unroll
      for (int d = 1; d < 16; d <<= 1) m = fmaxf(m, __shfl_xor(m, d));
      float e = __expf(s - m);
      float sum = e;
#pragma unroll
      for (int d = 1; d < 16; d <<= 1) sum += __shfl_xor(sum, d);
      Ss[(q5 * 12 + h) * 16 + w] = e / sum;
    }
  }
  __syncthreads();

  // PV: 5q x 96 d8-chunks = 480 items; per-w V reads 96-lane contiguous
  for (int idx = tid; idx < 480; idx += 256) {
    int d8 = idx % 96, q5 = idx / 96;
    int h = d8 >> 3;
    const float* arow = &Ss[(q5 * 12 + h) * 16];
    const unsigned short* vbase = &kv[pp * 24576 + 12288 + d8 * 8];
    f32x2 a0 = {0.f, 0.f}, a1 = {0.f, 0.f}, a2v = {0.f, 0.f}, a3 = {0.f, 0.f};
#pragma unroll
    for (int w = 0; w < 16; ++w) {
      uint4 vv = *(const uint4*)&vbase[(long)w * 768];
      float aw = arow[w];
      f32x2 aw2 = {aw, aw};
      pkfma(a0,  bf2x(vv.x), aw2);
      pkfma(a1,  bf2x(vv.y), aw2);
      pkfma(a2v, bf2x(vv.z), aw2);
      pkfma(a3,  bf2x(vv.w), aw2);
    }
    uint4 pk;
    pk.x = cvtpk(a0[0],  a0[1]);
    pk.y = cvtpk(a1[0],  a1[1]);
    pk.z = cvtpk(a2v[0], a2v[1]);
    pk.w = cvtpk(a3[0],  a3[1]);
    *(uint4*)&o[(pp * 5 + q5) * 768 + d8 * 8] = pk;
  }
}

// ---------------------------------------------------------------------------
extern "C" void kernel_launch(void* const* d_in, const int* in_sizes, int n_in,
                              void* d_out, int out_size, void* d_ws, size_t ws_size,
                              hipStream_t stream) {
  const float* x      = (const float*)d_in[0];   // [32,576,1536]
  const float* y      = (const float*)d_in[1];   // [32,9216,1024]
  const float* Wx     = (const float*)d_in[2];   // [768,1536]
  const float* bx     = (const float*)d_in[3];   // [768]
  const float* Wy     = (const float*)d_in[4];   // [768,1024]
  const float* by     = (const float*)d_in[5];   // [768]
  const float* prompt = (const float*)d_in[6];   // [1,4,768]
  const float* ipw    = (const float*)d_in[7];   // [2304,768]
  const float* ipb    = (const float*)d_in[8];   // [2304]
  const float* outw   = (const float*)d_in[9];   // [768,768]
  const float* outb   = (const float*)d_in[10];  // [768]
  float* out = (float*)d_out;

  char* ws = (char*)d_ws;
  size_t off = 0;
  auto alloc = [&](size_t bytes) -> void* {
    void* p = ws + off; off += (bytes + 255) & ~(size_t)255; return p;
  };
  unsigned short* kvb  = (unsigned short*)alloc(294912UL * 1536 * 2);  // 906 MB
  unsigned short* qxb  = (unsigned short*)alloc(18432UL * 768 * 2);    // 28 MB
  unsigned short* ob   = (unsigned short*)alloc(92160UL * 768 * 2);    // 142 MB
  unsigned short* Wqx  = (unsigned short*)alloc(768UL * 1536 * 2);
  unsigned short* Wkv  = (unsigned short*)alloc(1536UL * 1024 * 2);
  unsigned short* oww  = (unsigned short*)alloc(768UL * 768 * 2);
  unsigned short* qpf  = (unsigned short*)alloc(4UL * 768 * 2);
  float*          bqx  = (float*)alloc(768 * 4);
  float*          bkv  = (float*)alloc(1536 * 4);
  unsigned short* ipwb = (unsigned short*)alloc(2304UL * 768 * 2);     // bf16 in_proj_w
  unsigned short* WxT  = (unsigned short*)alloc(1536UL * 768 * 2);     // Wx^T bf16
  unsigned short* WyT  = (unsigned short*)alloc(1024UL * 768 * 2);     // Wy^T bf16
  float*          zb   = (float*)alloc(1536 * 4);                      // zero bias
  unsigned short* xb   = ob;  // alias (dead before k_attn writes ob)
  unsigned short* ybc  = (unsigned short*)(ws + off);
  long rpc = (long)((ws_size - off) / (1024 * 2)) & ~255L;  // rows/chunk, mult of 256
  if (rpc > 294912) rpc = 294912;
  if (rpc < 256) rpc = 256;

  // ---- weight prep ----
  k_cvt<<<dim3(288), dim3(256), 0, stream>>>(outw, oww, 768L * 768 / 8);
  k_cvt<<<dim3(864), dim3(256), 0, stream>>>(ipw, ipwb, 2304L * 768 / 8);
  k_tr<<<dim3(48, 24), dim3(256), 0, stream>>>(Wx, WxT, 768, 1536);
  k_tr<<<dim3(32, 24), dim3(256), 0, stream>>>(Wy, WyT, 768, 1024);
  k_zf<<<dim3(6), dim3(256), 0, stream>>>(zb, 1536);
  // fused weights via MFMA GEMM: Wqx = Wq @ Wx  (M=768, N=1536, K=768)
  k_gemm<unsigned short><<<dim3(6 * 12), dim3(256), 0, stream>>>(
      ipwb, WxT, zb, Wqx, 768, 1536, 768, 12);
  // Wk@Wy, Wv@Wy  (M=768, N=1024, K=768)
  k_gemm<unsigned short><<<dim3(6 * 8), dim3(256), 0, stream>>>(
      ipwb + 768 * 768, WyT, zb, Wkv, 768, 1024, 768, 8);
  k_gemm<unsigned short><<<dim3(6 * 8), dim3(256), 0, stream>>>(
      ipwb + 1536 * 768, WyT, zb, Wkv + 768 * 1024, 768, 1024, 768, 8);
  k_bfuse<<<dim3(576), dim3(256), 0, stream>>>(ipw, ipb, bx, by, bqx, bkv);
  k_qprompt<<<dim3(768), dim3(256), 0, stream>>>(ipw, ipb, prompt, qpf);

  // ---- x -> bf16; q_x = xb @ Wqx^T + bqx  (M=18432, N=768, K=1536) ----
  k_cvt<<<dim3(2048), dim3(256), 0, stream>>>(x, xb, 18432L * 1536 / 8);
  k_gemm<unsigned short><<<dim3(144 * 6), dim3(256), 0, stream>>>(
      xb, Wqx, bqx, qxb, 18432, 768, 1536, 6);

  // ---- kv = bf16(y) @ Wkv^T + bkv  (M=294912, N=1536, K=1024), 8-phase,
  //      written in attention layout (KVL=true) ----
  long row0 = 0;
  while (row0 < 294912) {
    long mc = 294912 - row0 < rpc ? 294912 - row0 : rpc;
    k_cvt<<<dim3(2048), dim3(256), 0, stream>>>(y + row0 * 1024, ybc, mc * 128);
    k_gemm8<true, unsigned short><<<dim3((int)(mc / 256) * 6), dim3(512), 0, stream>>>(
        ybc, Wkv, bkv, kvb + row0 * 1536, (int)mc, 1536, 1024, 6);
    row0 += mc;
  }

  // ---- attention -> o bf16 (1 patch per block, LDS-light) ----
  k_attn<<<dim3(18432), dim3(256), 0, stream>>>(kvb, qxb, qpf, ob);

  // ---- out = o @ oww^T + outb  (M=92160, N=768, K=768) -> f32, 8-phase ----
  k_gemm8<false, float><<<dim3(360 * 3), dim3(512), 0, stream>>>(
      ob, oww, outb, out, 92160, 768, 768, 3);
}

// Round 12
// 1958.204 us; speedup vs baseline: 3.8045x; 1.0728x over previous
//
#include <hip/hip_runtime.h>
#include <hip/hip_bf16.h>

// ---------------------------------------------------------------------------
// LocalizedPromptedAttentionLayer on MI355X (gfx950) — round 12
// B=32, N=576 patches, W=16 kv-window, d=768, P=4 prompts, H=12 heads, Dh=64
//
//   xb   = bf16(x)                                [18432, 1536]  (aliased in ob)
//   q_x  = xb @ (Wq@Wx)^T + (bq + Wq@bx)          [18432, 768] bf16   (128² GEMM)
//   qprm = prompt @ Wq^T + bq                     [4, 768] bf16
//   yb   = bf16(y)  chunked+PIPELINED             [rows, 1024]
//   kv   = yb @ [Wk@Wy ; Wv@Wy]^T + bias          [294912, 1536] bf16 (LINEAR layout,
//                                                  fat kernel: gemm(chunk i) ∥ cvt(chunk i+1))
//   o    = softmax(q k^T / 8) v                   [92160, 768] bf16
//   out  = o @ out_w^T + out_b                    [92160, 768] f32    (256² 8-phase)
//
// Round-12 vs round 11:
//  * kv GEMM epilogue reverted to linear (r11's KVL scatter cost 11% VALU).
//  * attn reads LINEAR kv coalesced via w-major lane map (lane=w*12+h:
//    12 lanes = 768B contiguous, all lines fully used); softmax via 2-phase
//    LDS handoff (scores -> barrier -> 16-lane shfl normalize).
//  * y-cvt hidden under kv GEMM: fat kernel = [128 cvt blocks (next chunk)]
//    + [gemm blocks (current chunk)], ping-pong ybc buffers, 4 chunks.
// ---------------------------------------------------------------------------

typedef __attribute__((ext_vector_type(8))) short bf16x8;   // MFMA A/B frag
typedef __attribute__((ext_vector_type(4))) float f32x4;    // MFMA C/D frag
typedef __attribute__((ext_vector_type(2))) float f32x2;
typedef __attribute__((ext_vector_type(8))) unsigned short u16x8;

__device__ __forceinline__ float bf2f(unsigned short u) {
  union { unsigned int i; float f; } x; x.i = ((unsigned int)u) << 16; return x.f;
}
__device__ __forceinline__ unsigned short f2b(float f) {
  union { float f; unsigned int i; } x; x.f = f;
  unsigned int u = x.i;
  return (unsigned short)((u + 0x7fffu + ((u >> 16) & 1u)) >> 16);  // RNE
}
__device__ __forceinline__ unsigned int cvtpk(float lo, float hi) {
  unsigned int r;
  asm("v_cvt_pk_bf16_f32 %0, %1, %2" : "=v"(r) : "v"(lo), "v"(hi));  // RNE pack
  return r;
}
// expand packed bf16 pair (one u32) to f32x2: lo = u<<16, hi = u&0xFFFF0000
__device__ __forceinline__ f32x2 bf2x(unsigned int u) {
  union { unsigned int i; float f; } lo, hi;
  lo.i = u << 16; hi.i = u & 0xFFFF0000u;
  f32x2 r; r[0] = lo.f; r[1] = hi.f; return r;
}
__device__ __forceinline__ void pkfma(f32x2& acc, f32x2 a, f32x2 b) {
  asm("v_pk_fma_f32 %0, %1, %2, %0" : "+v"(acc) : "v"(a), "v"(b));
}

#define GLDS(gaddr, laddr) \
  __builtin_amdgcn_global_load_lds( \
      (const __attribute__((address_space(1))) unsigned int*)(gaddr), \
      (__attribute__((address_space(3))) unsigned int*)(laddr), 16, 0, 0)

// ---------------- f32 -> bf16 bulk convert (8 elems/thread-iter) ----------------
__device__ __forceinline__ void cvt_body(const float* __restrict__ src,
                                         unsigned short* __restrict__ dst,
                                         long n8, long start, long stride) {
  for (long i = start; i < n8; i += stride) {
    float4 a = ((const float4*)src)[2 * i];
    float4 b = ((const float4*)src)[2 * i + 1];
    u16x8 t = { f2b(a.x), f2b(a.y), f2b(a.z), f2b(a.w),
                f2b(b.x), f2b(b.y), f2b(b.z), f2b(b.w) };
    ((u16x8*)dst)[i] = t;
  }
}

__global__ void k_cvt(const float* __restrict__ src, unsigned short* __restrict__ dst, long n8) {
  cvt_body(src, dst, n8, (long)blockIdx.x * blockDim.x + threadIdx.x,
           (long)gridDim.x * blockDim.x);
}

// ---------------- tiled transpose: src[R][C] f32 -> dst[C][R] bf16 ----------------
__global__ __launch_bounds__(256) void k_tr(const float* __restrict__ src,
                                            unsigned short* __restrict__ dst,
                                            int R, int C) {
  __shared__ float t[32][33];
  int bx = blockIdx.x * 32, by = blockIdx.y * 32;
  int lx = threadIdx.x & 31, ly = threadIdx.x >> 5;   // 32 x 8
#pragma unroll
  for (int s = 0; s < 32; s += 8)
    t[ly + s][lx] = src[(long)(by + ly + s) * C + bx + lx];
  __syncthreads();
#pragma unroll
  for (int s = 0; s < 32; s += 8)
    dst[(long)(bx + ly + s) * R + by + lx] = f2b(t[lx][ly + s]);
}

// ---------------- zero fill ----------------
__global__ void k_zf(float* __restrict__ p, int n) {
  int i = blockIdx.x * 256 + threadIdx.x;
  if (i < n) p[i] = 0.f;
}

// ---------------- fused biases ----------------
__global__ void k_bfuse(const float* __restrict__ ipw, const float* __restrict__ ipb,
                        const float* __restrict__ bx, const float* __restrict__ by,
                        float* __restrict__ bqx, float* __restrict__ bkv) {
  int o    = blockIdx.x * 4 + (threadIdx.x >> 6);   // 0..2303 (grid 576)
  int lane = threadIdx.x & 63;
  int sec  = o / 768, jj = o - sec * 768;
  const float* Arow = ipw + (long)o * 768;
  const float* vb   = (sec == 0) ? bx : by;
  float s = 0.f;
  for (int k = lane; k < 768; k += 64) s += Arow[k] * vb[k];
#pragma unroll
  for (int d = 32; d > 0; d >>= 1) s += __shfl_down(s, d);
  if (lane == 0) {
    s += ipb[o];
    if (sec == 0) bqx[jj] = s;
    else if (sec == 1) bkv[jj] = s;
    else bkv[768 + jj] = s;
  }
}

// ---------------- prompt queries ----------------
__global__ void k_qprompt(const float* __restrict__ ipw, const float* __restrict__ ipb,
                          const float* __restrict__ prompt, unsigned short* __restrict__ qpf) {
  int o    = blockIdx.x * 4 + (threadIdx.x >> 6);   // 0..3071 (grid 768)
  int lane = threadIdx.x & 63;
  int p = o / 768, j = o - p * 768;
  const float* Wqr = ipw + (long)j * 768;
  const float* pr  = prompt + (long)p * 768;
  float s = 0.f;
  for (int k = lane; k < 768; k += 64) s += Wqr[k] * pr[k];
#pragma unroll
  for (int d = 32; d > 0; d >>= 1) s += __shfl_down(s, d);
  if (lane == 0) qpf[o] = f2b(s + ipb[j]);
}

// ---------------- 128² GEMM (proven m97 structure) ----------------
template <typename OutT>
__global__ __launch_bounds__(256) void k_gemm(const unsigned short* __restrict__ A,
                                              const unsigned short* __restrict__ Bw,
                                              const float* __restrict__ bias,
                                              OutT* __restrict__ C,
                                              int M, int Nn, int K, int nbx) {
  const int tid  = threadIdx.x;
  const int lane = tid & 63, wid = tid >> 6;
  const int wm = wid >> 1, wn = wid & 1;
  const int lr = lane & 15, lk = lane >> 4;

  const int nwg = gridDim.x, orig = blockIdx.x;
  const int q8 = nwg >> 3, r8 = nwg & 7, xc = orig & 7;
  const int wg = (xc < r8 ? xc * (q8 + 1) : r8 * (q8 + 1) + (xc - r8) * q8) + (orig >> 3);
  const int bn = wg % nbx, bm = wg / nbx;
  const int m0 = bm * 128, n0 = bn * 128;

  __shared__ __attribute__((aligned(16))) unsigned short As[2][128 * 32];
  __shared__ __attribute__((aligned(16))) unsigned short Bs[2][128 * 32];

  f32x4 acc[4][4];
#pragma unroll
  for (int nt = 0; nt < 4; ++nt) {
    float bv = bias[n0 + wn * 64 + nt * 16 + lr];
    f32x4 bvv = {bv, bv, bv, bv};
#pragma unroll
    for (int mt = 0; mt < 4; ++mt) acc[mt][nt] = bvv;
  }

  const int NS = K >> 5;
  const int crow = lane >> 2, ck8 = (lane & 3) * 8;

  auto stage = [&](int buf, int ks) {
#pragma unroll
    for (int i = 0; i < 2; ++i) {
      int c = wid * 2 + i;
      int row = c * 16 + crow;
      GLDS(&A[(long)(m0 + row) * K + ks * 32 + ck8], &As[buf][c * 512]);
      GLDS(&Bw[(long)(n0 + row) * K + ks * 32 + ck8], &Bs[buf][c * 512]);
    }
  };

  stage(0, 0);
  __syncthreads();

  for (int t = 0; t < NS; ++t) {
    const int cur = t & 1, nb = cur ^ 1;
    if (t + 1 < NS) stage(nb, t + 1);
    bf16x8 af[4], bfr[4];
#pragma unroll
    for (int mt = 0; mt < 4; ++mt)
      af[mt] = *(const bf16x8*)&As[cur][(wm * 64 + mt * 16 + lr) * 32 + lk * 8];
#pragma unroll
    for (int nt = 0; nt < 4; ++nt)
      bfr[nt] = *(const bf16x8*)&Bs[cur][(wn * 64 + nt * 16 + lr) * 32 + lk * 8];
#pragma unroll
    for (int mt = 0; mt < 4; ++mt)
#pragma unroll
      for (int nt = 0; nt < 4; ++nt)
        acc[mt][nt] = __builtin_amdgcn_mfma_f32_16x16x32_bf16(af[mt], bfr[nt], acc[mt][nt], 0, 0, 0);
    __syncthreads();
  }

#pragma unroll
  for (int mt = 0; mt < 4; ++mt)
#pragma unroll
    for (int nt = 0; nt < 4; ++nt) {
      int col = n0 + wn * 64 + nt * 16 + lr;
#pragma unroll
      for (int r = 0; r < 4; ++r) {
        int row = m0 + wm * 64 + mt * 16 + lk * 4 + r;
        float v = acc[mt][nt][r];
        if constexpr (sizeof(OutT) == 4) C[(long)row * Nn + col] = v;
        else                             C[(long)row * Nn + col] = f2b(v);
      }
    }
}

// ---------------- 256² 8-phase GEMM body (round-5/9 proven schedule) ----------------
template <typename OutT>
__device__ __forceinline__ void gemm8_body(const unsigned short* __restrict__ A,
                                           const unsigned short* __restrict__ Bw,
                                           const float* __restrict__ bias,
                                           OutT* __restrict__ C,
                                           int M, int Nn, int K, int nbx,
                                           int orig, int nwg) {
  const int tid  = threadIdx.x;
  const int lane = tid & 63, wid = tid >> 6;
  const int wm = wid >> 2, wn = wid & 3;          // 2 x 4 waves
  const int lr = lane & 15, lk = lane >> 4;

  const int q8 = nwg >> 3, r8 = nwg & 7, xc = orig & 7;
  const int wg = (xc < r8 ? xc * (q8 + 1) : r8 * (q8 + 1) + (xc - r8) * q8) + (orig >> 3);
  const int bn = wg % nbx, bm = wg / nbx;
  const long m0 = (long)bm * 256, n0 = (long)bn * 256;

  __shared__ __attribute__((aligned(16))) unsigned short As[2][2][8192];  // [buf][half][128*64]
  __shared__ __attribute__((aligned(16))) unsigned short Bs[2][2][8192];

  f32x4 acc[8][4];
#pragma unroll
  for (int nt = 0; nt < 4; ++nt) {
    float bv = bias[n0 + wn * 64 + nt * 16 + lr];
    f32x4 bvv = {bv, bv, bv, bv};
#pragma unroll
    for (int mt = 0; mt < 8; ++mt) acc[mt][nt] = bvv;
  }

  const int NT = K >> 6;            // K-tiles of 64

  auto stage = [&](int buf, int kt, int isB, int h) {
#pragma unroll
    for (int j = 0; j < 2; ++j) {
      int c   = j * 8 + wid;                         // 1KB chunk (wave-uniform)
      int row = c * 8 + (lane >> 3);                 // 0..127
      int col = ((lane & 7) * 8) ^ ((row & 7) << 3); // elems, inverse-swizzled
      const unsigned short* g = isB
          ? &Bw[(n0 + h * 128 + row) * (long)K + kt * 64 + col]
          : &A [(m0 + h * 128 + row) * (long)K + kt * 64 + col];
      unsigned short* l = isB ? &Bs[buf][h][c * 512] : &As[buf][h][c * 512];
      GLDS(g, l);
    }
  };
  auto ldsA = [&](int buf, int mt, int kk) -> bf16x8 {
    int r = mt * 16 + lr;
    int off = r * 128 + ((kk * 64 + lk * 16) ^ ((lr & 7) << 4));   // bytes
    return *(const bf16x8*)((const char*)&As[buf][wm][0] + off);
  };
  auto ldsB = [&](int buf, int nt, int kk) -> bf16x8 {
    int r = (wn & 1) * 64 + nt * 16 + lr;
    int off = r * 128 + ((kk * 64 + lk * 16) ^ ((lr & 7) << 4));
    return *(const bf16x8*)((const char*)&Bs[buf][wn >> 1][0] + off);
  };

  // ---- prologue: tile0 (all 4 halves) + tile1 A-half0 ----
  stage(0, 0, 0, 0); stage(0, 0, 0, 1); stage(0, 0, 1, 0); stage(0, 0, 1, 1);
  if (NT > 1) {
    stage(1, 1, 0, 0);
    asm volatile("s_waitcnt vmcnt(2)" ::: "memory");
  } else {
    asm volatile("s_waitcnt vmcnt(0)" ::: "memory");
  }
  __builtin_amdgcn_s_barrier();

  for (int u = 0; u < NT; ++u) {
    const int cb = u & 1;
    bf16x8 a[4][2], b0[2][2], b1[2][2];

    // ---- P1 ----
#pragma unroll
    for (int mt = 0; mt < 4; ++mt) { a[mt][0] = ldsA(cb, mt, 0); a[mt][1] = ldsA(cb, mt, 1); }
#pragma unroll
    for (int nt = 0; nt < 2; ++nt) { b0[nt][0] = ldsB(cb, nt, 0); b0[nt][1] = ldsB(cb, nt, 1); }
    if (u + 1 < NT) stage(cb ^ 1, u + 1, 0, 1);
    __builtin_amdgcn_s_barrier();
    asm volatile("s_waitcnt lgkmcnt(0)" ::: "memory");
    __builtin_amdgcn_s_setprio(1);
#pragma unroll
    for (int mt = 0; mt < 4; ++mt)
#pragma unroll
      for (int nt = 0; nt < 2; ++nt)
#pragma unroll
        for (int kk = 0; kk < 2; ++kk)
          acc[mt][nt] = __builtin_amdgcn_mfma_f32_16x16x32_bf16(a[mt][kk], b0[nt][kk], acc[mt][nt], 0, 0, 0);
    __builtin_amdgcn_s_setprio(0);
    __builtin_amdgcn_s_barrier();

    // ---- P2 ----
#pragma unroll
    for (int nt = 0; nt < 2; ++nt) { b1[nt][0] = ldsB(cb, 2 + nt, 0); b1[nt][1] = ldsB(cb, 2 + nt, 1); }
    if (u + 1 < NT) stage(cb ^ 1, u + 1, 1, 0);
    __builtin_amdgcn_s_barrier();
    asm volatile("s_waitcnt lgkmcnt(0)" ::: "memory");
    __builtin_amdgcn_s_setprio(1);
#pragma unroll
    for (int mt = 0; mt < 4; ++mt)
#pragma unroll
      for (int nt = 0; nt < 2; ++nt)
#pragma unroll
        for (int kk = 0; kk < 2; ++kk)
          acc[mt][2 + nt] = __builtin_amdgcn_mfma_f32_16x16x32_bf16(a[mt][kk], b1[nt][kk], acc[mt][2 + nt], 0, 0, 0);
    __builtin_amdgcn_s_setprio(0);
    __builtin_amdgcn_s_barrier();

    // ---- P3 ----
#pragma unroll
    for (int mt = 0; mt < 4; ++mt) { a[mt][0] = ldsA(cb, 4 + mt, 0); a[mt][1] = ldsA(cb, 4 + mt, 1); }
    if (u + 1 < NT) stage(cb ^ 1, u + 1, 1, 1);
    __builtin_amdgcn_s_barrier();
    asm volatile("s_waitcnt lgkmcnt(0)" ::: "memory");
    __builtin_amdgcn_s_setprio(1);
#pragma unroll
    for (int mt = 0; mt < 4; ++mt)
#pragma unroll
      for (int nt = 0; nt < 2; ++nt)
#pragma unroll
        for (int kk = 0; kk < 2; ++kk)
          acc[4 + mt][2 + nt] = __builtin_amdgcn_mfma_f32_16x16x32_bf16(a[mt][kk], b1[nt][kk], acc[4 + mt][2 + nt], 0, 0, 0);
    __builtin_amdgcn_s_setprio(0);
    __builtin_amdgcn_s_barrier();

    // ---- P4 ----
    if (u + 2 < NT) stage(cb, u + 2, 0, 0);
    __builtin_amdgcn_s_barrier();
    __builtin_amdgcn_s_setprio(1);
#pragma unroll
    for (int mt = 0; mt < 4; ++mt)
#pragma unroll
      for (int nt = 0; nt < 2; ++nt)
#pragma unroll
        for (int kk = 0; kk < 2; ++kk)
          acc[4 + mt][nt] = __builtin_amdgcn_mfma_f32_16x16x32_bf16(a[mt][kk], b0[nt][kk], acc[4 + mt][nt], 0, 0, 0);
    __builtin_amdgcn_s_setprio(0);
    // counted drain BEFORE the closing barrier (cross-wave publish, r5 rule)
    if (u + 2 < NT)       asm volatile("s_waitcnt vmcnt(2)" ::: "memory");
    else if (u + 1 < NT)  asm volatile("s_waitcnt vmcnt(0)" ::: "memory");
    __builtin_amdgcn_s_barrier();
  }

  // ---- epilogue (linear) ----
#pragma unroll
  for (int mt = 0; mt < 8; ++mt)
#pragma unroll
    for (int nt = 0; nt < 4; ++nt) {
      long col = n0 + wn * 64 + nt * 16 + lr;
#pragma unroll
      for (int r = 0; r < 4; ++r) {
        long row = m0 + wm * 128 + mt * 16 + lk * 4 + r;
        float v = acc[mt][nt][r];
        if constexpr (sizeof(OutT) == 4) C[row * Nn + col] = v;
        else                             C[row * Nn + col] = f2b(v);
      }
    }
}

template <typename OutT>
__global__ __launch_bounds__(512, 2) void k_gemm8(const unsigned short* __restrict__ A,
                                                  const unsigned short* __restrict__ Bw,
                                                  const float* __restrict__ bias,
                                                  OutT* __restrict__ C,
                                                  int M, int Nn, int K, int nbx) {
  gemm8_body<OutT>(A, Bw, bias, C, M, Nn, K, nbx, blockIdx.x, gridDim.x);
}

// ---------------- fat kernel: [ncvt cvt blocks (next chunk)] + [gemm blocks] ----------------
__global__ __launch_bounds__(512, 2) void k_kvfat(const unsigned short* __restrict__ A,
                                                  const unsigned short* __restrict__ Bw,
                                                  const float* __restrict__ bias,
                                                  unsigned short* __restrict__ C,
                                                  int M, int Nn, int K, int nbx,
                                                  const float* __restrict__ ysrc,
                                                  unsigned short* __restrict__ ydst,
                                                  long n8, int ncvt) {
  if ((int)blockIdx.x < ncvt) {
    cvt_body(ysrc, ydst, n8, (long)blockIdx.x * 512 + threadIdx.x, (long)ncvt * 512);
    return;
  }
  gemm8_body<unsigned short>(A, Bw, bias, C, M, Nn, K, nbx,
                             (int)blockIdx.x - ncvt, (int)gridDim.x - ncvt);
}

// ---------------- attention: LDS-light, coalesced linear K (w-major lanes) ----------------
// 1 patch / 256 threads, LDS ~11.3 KB. Scores: lane = w*12+h (12 consecutive
// lanes read 768B contiguous K). Softmax: raw scores -> LDS -> barrier ->
// 16-lane shfl normalize. PV: per-w V reads 96-lane contiguous (stride 1536).
__global__ __launch_bounds__(256, 6) void k_attn(const unsigned short* __restrict__ kv,
                                                 const unsigned short* __restrict__ qx,
                                                 const unsigned short* __restrict__ qp,
                                                 unsigned short* __restrict__ o) {
  __shared__ __attribute__((aligned(16))) unsigned short Qs[5 * 768];
  __shared__ float Ss[60 * 16];
  const int tid = threadIdx.x;
  const long pp = (long)blockIdx.x;          // patch id 0..18431

  // stage Q bf16: row0 = qx[pp], rows 1-4 = prompts
  for (int i = tid; i < 5 * 96; i += 256) {
    int r = i / 96, c8 = i - r * 96;
    const unsigned short* src = (r == 0) ? &qx[pp * 768 + c8 * 8]
                                         : &qp[(long)(r - 1) * 768 + c8 * 8];
    *(u16x8*)&Qs[r * 768 + c8 * 8] = *(const u16x8*)src;
  }
  __syncthreads();

  // scores (raw): lane = w*12 + h (192 active); K read 128B/lane,
  // 12 consecutive lanes = 768B contiguous (every 64B line fully used)
  if (tid < 192) {
    const int w = tid / 12, h = tid - (tid / 12) * 12;
    const uint4* kr = (const uint4*)&kv[(pp * 16 + w) * 1536 + h * 64];
    f32x2 s2[5];
#pragma unroll
    for (int q5 = 0; q5 < 5; ++q5) { s2[q5][0] = 0.f; s2[q5][1] = 0.f; }
#pragma unroll
    for (int half = 0; half < 2; ++half) {
      uint4 kk0 = kr[half * 4 + 0], kk1 = kr[half * 4 + 1],
            kk2 = kr[half * 4 + 2], kk3 = kr[half * 4 + 3];
#pragma unroll
      for (int q5 = 0; q5 < 5; ++q5) {
        const uint4* qr = (const uint4*)&Qs[q5 * 768 + h * 64 + half * 32];
#pragma unroll
        for (int j = 0; j < 4; ++j) {
          uint4 kkj = (j == 0) ? kk0 : (j == 1) ? kk1 : (j == 2) ? kk2 : kk3;
          uint4 qw = qr[j];
          pkfma(s2[q5], bf2x(kkj.x), bf2x(qw.x));
          pkfma(s2[q5], bf2x(kkj.y), bf2x(qw.y));
          pkfma(s2[q5], bf2x(kkj.z), bf2x(qw.z));
          pkfma(s2[q5], bf2x(kkj.w), bf2x(qw.w));
        }
      }
    }
#pragma unroll
    for (int q5 = 0; q5 < 5; ++q5)
      Ss[(q5 * 12 + h) * 16 + w] = (s2[q5][0] + s2[q5][1]) * 0.125f;
  }
  __syncthreads();

  // softmax normalize: 960 items, 16-lane w-groups (aligned: idx ≡ tid mod 16)
  for (int idx = tid; idx < 960; idx += 256) {
    int w = idx & 15, rest = idx >> 4;
    float s = Ss[rest * 16 + w];
    float m = s;
#pragma unroll
    for (int d = 1; d < 16; d <<= 1) m = fmaxf(m, __shfl_xor(m, d));
    float e = __expf(s - m);
    float sum = e;
#pragma unroll
    for (int d = 1; d < 16; d <<= 1) sum += __shfl_xor(sum, d);
    Ss[rest * 16 + w] = e / sum;
  }
  __syncthreads();

  // PV: 5q x 96 d8-chunks = 480 items; per-w V reads 96-lane contiguous
  for (int idx = tid; idx < 480; idx += 256) {
    int d8 = idx % 96, q5 = idx / 96;
    int h = d8 >> 3;
    const float* arow = &Ss[(q5 * 12 + h) * 16];
    const unsigned short* vbase = &kv[pp * 24576 + 768 + d8 * 8];
    f32x2 a0 = {0.f, 0.f}, a1 = {0.f, 0.f}, a2v = {0.f, 0.f}, a3 = {0.f, 0.f};
#pragma unroll
    for (int w = 0; w < 16; ++w) {
      uint4 vv = *(const uint4*)&vbase[(long)w * 1536];
      float aw = arow[w];
      f32x2 aw2 = {aw, aw};
      pkfma(a0,  bf2x(vv.x), aw2);
      pkfma(a1,  bf2x(vv.y), aw2);
      pkfma(a2v, bf2x(vv.z), aw2);
      pkfma(a3,  bf2x(vv.w), aw2);
    }
    uint4 pk;
    pk.x = cvtpk(a0[0],  a0[1]);
    pk.y = cvtpk(a1[0],  a1[1]);
    pk.z = cvtpk(a2v[0], a2v[1]);
    pk.w = cvtpk(a3[0],  a3[1]);
    *(uint4*)&o[(pp * 5 + q5) * 768 + d8 * 8] = pk;
  }
}

// ---------------------------------------------------------------------------
extern "C" void kernel_launch(void* const* d_in, const int* in_sizes, int n_in,
                              void* d_out, int out_size, void* d_ws, size_t ws_size,
                              hipStream_t stream) {
  const float* x      = (const float*)d_in[0];   // [32,576,1536]
  const float* y      = (const float*)d_in[1];   // [32,9216,1024]
  const float* Wx     = (const float*)d_in[2];   // [768,1536]
  const float* bx     = (const float*)d_in[3];   // [768]
  const float* Wy     = (const float*)d_in[4];   // [768,1024]
  const float* by     = (const float*)d_in[5];   // [768]
  const float* prompt = (const float*)d_in[6];   // [1,4,768]
  const float* ipw    = (const float*)d_in[7];   // [2304,768]
  const float* ipb    = (const float*)d_in[8];   // [2304]
  const float* outw   = (const float*)d_in[9];   // [768,768]
  const float* outb   = (const float*)d_in[10];  // [768]
  float* out = (float*)d_out;

  char* ws = (char*)d_ws;
  size_t off = 0;
  auto alloc = [&](size_t bytes) -> void* {
    void* p = ws + off; off += (bytes + 255) & ~(size_t)255; return p;
  };
  unsigned short* kvb  = (unsigned short*)alloc(294912UL * 1536 * 2);  // 906 MB
  unsigned short* qxb  = (unsigned short*)alloc(18432UL * 768 * 2);    // 28 MB
  unsigned short* ob   = (unsigned short*)alloc(92160UL * 768 * 2);    // 142 MB
  unsigned short* Wqx  = (unsigned short*)alloc(768UL * 1536 * 2);
  unsigned short* Wkv  = (unsigned short*)alloc(1536UL * 1024 * 2);
  unsigned short* oww  = (unsigned short*)alloc(768UL * 768 * 2);
  unsigned short* qpf  = (unsigned short*)alloc(4UL * 768 * 2);
  float*          bqx  = (float*)alloc(768 * 4);
  float*          bkv  = (float*)alloc(1536 * 4);
  unsigned short* ipwb = (unsigned short*)alloc(2304UL * 768 * 2);     // bf16 in_proj_w
  unsigned short* WxT  = (unsigned short*)alloc(1536UL * 768 * 2);     // Wx^T bf16
  unsigned short* WyT  = (unsigned short*)alloc(1024UL * 768 * 2);     // Wy^T bf16
  float*          zb   = (float*)alloc(1536 * 4);                      // zero bias
  unsigned short* xb   = ob;  // alias (dead before k_attn writes ob)

  // ping-pong y bf16 chunk buffers
  long rpc = (long)((ws_size - off) / (1024 * 2 * 2)) & ~255L;  // rows/chunk
  if (rpc > 73728) rpc = 73728;    // 4 chunks -> pipelined cvt mostly hidden
  if (rpc < 256) rpc = 256;
  unsigned short* ybc0 = (unsigned short*)(ws + off);
  unsigned short* ybc1 = ybc0 + rpc * 1024;

  // ---- weight prep ----
  k_cvt<<<dim3(288), dim3(256), 0, stream>>>(outw, oww, 768L * 768 / 8);
  k_cvt<<<dim3(864), dim3(256), 0, stream>>>(ipw, ipwb, 2304L * 768 / 8);
  k_tr<<<dim3(48, 24), dim3(256), 0, stream>>>(Wx, WxT, 768, 1536);
  k_tr<<<dim3(32, 24), dim3(256), 0, stream>>>(Wy, WyT, 768, 1024);
  k_zf<<<dim3(6), dim3(256), 0, stream>>>(zb, 1536);
  k_gemm<unsigned short><<<dim3(6 * 12), dim3(256), 0, stream>>>(
      ipwb, WxT, zb, Wqx, 768, 1536, 768, 12);
  k_gemm<unsigned short><<<dim3(6 * 8), dim3(256), 0, stream>>>(
      ipwb + 768 * 768, WyT, zb, Wkv, 768, 1024, 768, 8);
  k_gemm<unsigned short><<<dim3(6 * 8), dim3(256), 0, stream>>>(
      ipwb + 1536 * 768, WyT, zb, Wkv + 768 * 1024, 768, 1024, 768, 8);
  k_bfuse<<<dim3(576), dim3(256), 0, stream>>>(ipw, ipb, bx, by, bqx, bkv);
  k_qprompt<<<dim3(768), dim3(256), 0, stream>>>(ipw, ipb, prompt, qpf);

  // ---- x -> bf16; q_x = xb @ Wqx^T + bqx  (M=18432, N=768, K=1536) ----
  k_cvt<<<dim3(2048), dim3(256), 0, stream>>>(x, xb, 18432L * 1536 / 8);
  k_gemm<unsigned short><<<dim3(144 * 6), dim3(256), 0, stream>>>(
      xb, Wqx, bqx, qxb, 18432, 768, 1536, 6);

  // ---- kv = bf16(y) @ Wkv^T + bkv, pipelined: gemm(chunk i) ∥ cvt(chunk i+1) ----
  {
    long mc0 = 294912 < rpc ? 294912 : rpc;
    k_cvt<<<dim3(2048), dim3(256), 0, stream>>>(y, ybc0, mc0 * 128);
    long row0 = 0; int pi = 0;
    while (row0 < 294912) {
      long mc = 294912 - row0 < rpc ? 294912 - row0 : rpc;
      long next0 = row0 + mc;
      long mcn = (next0 < 294912) ? ((294912 - next0 < rpc) ? 294912 - next0 : rpc) : 0;
      int ngemm = (int)(mc / 256) * 6;
      int ncvt  = mcn ? 128 : 0;
      unsigned short* cur = (pi & 1) ? ybc1 : ybc0;
      unsigned short* nxt = (pi & 1) ? ybc0 : ybc1;
      k_kvfat<<<dim3(ngemm + ncvt), dim3(512), 0, stream>>>(
          cur, Wkv, bkv, kvb + row0 * 1536, (int)mc, 1536, 1024, 6,
          y + next0 * 1024, nxt, mcn * 128, ncvt);
      row0 = next0; ++pi;
    }
  }

  // ---- attention -> o bf16 (1 patch per block, LDS-light) ----
  k_attn<<<dim3(18432), dim3(256), 0, stream>>>(kvb, qxb, qpf, ob);

  // ---- out = o @ oww^T + outb  (M=92160, N=768, K=768) -> f32, 8-phase ----
  k_gemm8<float><<<dim3(360 * 3), dim3(512), 0, stream>>>(
      ob, oww, outb, out, 92160, 768, 768, 3);
}